// Round 4
// baseline (416.162 us; speedup 1.0000x reference)
//
#include <hip/hip_runtime.h>
#include <hip/hip_bf16.h>
#include <hip/hip_fp16.h>

// Problem constants: B=8, N=10000, E=160000, F=128, H=256
#define Bn 8
#define Nn 10000
#define En 160000
#define Fn 128
#define Hn 256
#define NROW (Bn * Nn)     // 80,000
#define NEDGE (Bn * En)    // 1,280,000
#define TM 32              // rows per block in fused epilogue

// Workspace layout (ints):
//   [0,80000)            deg (int) -> dinv (f32) after k_scan3
//   [80000,160001)       row_start
//   [160004,240004)      cursor
//   [240004,240317)      bsum (313)
//   [240320,240832)      boff (512)
//   [240832,1520832)     elist (global src per edge, CSR order)
//   [1520832,2800832)    wlist (dinv[src] per edge)  [tier >= 2]
//   then 458,752 B packed split-bf16 weights (u16), 16B-aligned
//   then (tier 3) 20,480,000 B x0 as f16 [NROW][128].
// Tier-2 out row layout (1024 B): [0,256)=AGG hi bf16, [256,512)=AGG lo,
//   [512,768)=x0 f16 copy. Tier-3: out is write-only (k_gfm stage C).
#define OFF_RS   80000
#define OFF_CUR  160004
#define OFF_BS   240004
#define OFF_BO   240320
#define OFF_EL   240832
#define OFF_WL   1520832
#define WS1_INTS 1520832
#define WS2_INTS 2800832
#define WP_BYTES 458752
#define X0H_BYTES ((size_t)NROW * Fn * 2)             // 20,480,000
#define WS1_BYTES ((size_t)WS1_INTS * 4 + WP_BYTES)   // 6,542,080
#define WS2_BYTES ((size_t)WS2_INTS * 4 + WP_BYTES)   // 11,662,080
#define WS3_BYTES (WS2_BYTES + X0H_BYTES)             // 32,142,080

typedef unsigned short u16;
typedef __attribute__((ext_vector_type(8))) short s16x8;
typedef __attribute__((ext_vector_type(4))) float f32x4;

__device__ __forceinline__ u16 f2bf(float x) {           // RNE f32->bf16
    unsigned u = __float_as_uint(x);
    u += 0x7FFF + ((u >> 16) & 1);
    return (u16)(u >> 16);
}
__device__ __forceinline__ float bf2f(u16 h) {
    return __uint_as_float((unsigned)h << 16);
}

__device__ __forceinline__ bool edge_is_i64(const int* e) {
    return e[1] == 0 && e[3] == 0;
}
__device__ __forceinline__ int eidx(const int* e, long long i, bool i64) {
    return i64 ? e[2 * i] : e[i];
}

// ---------------------------------------------------------------------------
// Tier-3 init: deg=1, canary poison, x0 -> f16 table in workspace.
// ---------------------------------------------------------------------------
__global__ void k_init3(int* __restrict__ deg, __half* __restrict__ x0h,
                        const float* __restrict__ x0, float* __restrict__ out) {
    int i = blockIdx.x * 256 + threadIdx.x;     // < NROW*32
    if (i >= NROW * 32) return;
    if (i < NROW) deg[i] = 1;
    if (i == 0) out[4] = 1000.0f;               // erased by k_gfm stage C
    int r = i >> 5, g = i & 31;
    float4 v = *(const float4*)(x0 + ((size_t)r << 7) + (g << 2));
    __half2 a = __floats2half2_rn(v.x, v.y);
    __half2 b = __floats2half2_rn(v.z, v.w);
    uint2 u;
    u.x = *(unsigned*)&a;
    u.y = *(unsigned*)&b;
    *(uint2*)((char*)x0h + ((size_t)r << 8) + (g << 3)) = u;
}

// Tier-2 init: deg=1 + canary.
__global__ void k_init(int* __restrict__ deg, float* __restrict__ out) {
    int i = blockIdx.x * blockDim.x + threadIdx.x;
    if (i < NROW) deg[i] = 1;
    if (i == 0) out[4] = 1000.0f;
}

// Tier-2: x0 -> f16 into out row bytes [512,768).
__global__ void k_xh(const float* __restrict__ x0, float* __restrict__ out) {
    int i = blockIdx.x * 256 + threadIdx.x;
    if (i >= NROW * 32) return;
    int r = i >> 5, g = i & 31;
    float4 v = *(const float4*)(x0 + ((size_t)r << 7) + (g << 2));
    __half2 a = __floats2half2_rn(v.x, v.y);
    __half2 b = __floats2half2_rn(v.z, v.w);
    uint2 u;
    u.x = *(unsigned*)&a;
    u.y = *(unsigned*)&b;
    *(uint2*)((char*)out + ((size_t)r << 10) + 512 + (g << 3)) = u;
}

__global__ void k_deg_count_i(const int* __restrict__ e, int* __restrict__ deg) {
    bool i64 = edge_is_i64(e);
    int i = blockIdx.x * blockDim.x + threadIdx.x;
    if (i >= NEDGE) return;
    int b = i / En, k = i - b * En;
    int dst = eidx(e, (long long)(b * 2 + 1) * En + k, i64);
    if ((unsigned)dst < Nn) atomicAdd(&deg[b * Nn + dst], 1);
}

// ---------------------------------------------------------------------------
// Exclusive scan of in-degree over 80,000 rows, 3 kernels.
// ---------------------------------------------------------------------------
__global__ void k_scan1(const int* __restrict__ deg,
                        int* __restrict__ row_start, int* __restrict__ bsum) {
    __shared__ int s[256];
    int i = blockIdx.x * 256 + threadIdx.x;
    int v = (i < NROW) ? (deg[i] - 1) : 0;
    s[threadIdx.x] = v;
    __syncthreads();
    for (int off = 1; off < 256; off <<= 1) {
        int t = (threadIdx.x >= off) ? s[threadIdx.x - off] : 0;
        __syncthreads();
        s[threadIdx.x] += t;
        __syncthreads();
    }
    if (i < NROW) row_start[i] = s[threadIdx.x] - v;
    if (threadIdx.x == 255) bsum[blockIdx.x] = s[255];
}

__global__ void k_scan2(const int* __restrict__ bsum, int* __restrict__ boff,
                        int* __restrict__ row_start) {
    __shared__ int s[512];
    int t = threadIdx.x;
    int v = (t < 313) ? bsum[t] : 0;
    s[t] = v;
    __syncthreads();
    for (int off = 1; off < 512; off <<= 1) {
        int u = (t >= off) ? s[t - off] : 0;
        __syncthreads();
        s[t] += u;
        __syncthreads();
    }
    boff[t] = s[t] - v;
    if (t == 511) row_start[NROW] = s[511];
}

__global__ void k_scan3(int* __restrict__ degi, float* __restrict__ dinvf,
                        int* __restrict__ row_start,
                        const int* __restrict__ boff, int* __restrict__ cursor) {
    int i = blockIdx.x * blockDim.x + threadIdx.x;
    if (i >= NROW) return;
    int v = row_start[i] + boff[i >> 8];
    row_start[i] = v;
    cursor[i] = v;
    float d = (float)degi[i];
    dinvf[i] = rsqrtf(d);
}

// ---------------------------------------------------------------------------
// Counting-sort edges by destination; optionally materialize weights.
// ---------------------------------------------------------------------------
__global__ void k_bin(const int* __restrict__ e, const float* __restrict__ dinv,
                      int* __restrict__ cursor, int* __restrict__ elist,
                      float* __restrict__ wl) {
    bool i64 = edge_is_i64(e);
    int i = blockIdx.x * blockDim.x + threadIdx.x;
    if (i >= NEDGE) return;
    int b = i / En, k = i - b * En;
    int src = eidx(e, (long long)(b * 2) * En + k, i64);
    int dst = eidx(e, (long long)(b * 2 + 1) * En + k, i64);
    if ((unsigned)src >= Nn || (unsigned)dst >= Nn) return;
    int gsrc = b * Nn + src;
    int pos = atomicAdd(&cursor[b * Nn + dst], 1);
    elist[pos] = gsrc;
    if (wl) wl[pos] = dinv[gsrc];
}

// ---------------------------------------------------------------------------
// Weight pre-split + pre-swizzle into MFMA B-fragment order.
// Per weight: [kt][nt][h(hi/lo)][lane 64][8 slots] of bf16 (u16).
// k-map: k = kt*32 + (l>>4)*8 + j (same map as A-frags).
// Regions (u16): Wc @0 (32768), W1 @32768 (65536), W2 @98304 (131072).
// ---------------------------------------------------------------------------
__global__ void k_wpack(const float* __restrict__ Wc, const float* __restrict__ W1,
                        const float* __restrict__ W2, u16* __restrict__ wp) {
    int i = blockIdx.x * 256 + threadIdx.x;
    const float* W; u16* dst; int NT, idx;
    if (i < 16384)       { W = Wc; dst = wp;         NT = 8;  idx = i; }
    else if (i < 49152)  { W = W1; dst = wp + 32768; NT = 16; idx = i - 16384; }
    else if (i < 114688) { W = W2; dst = wp + 98304; NT = 16; idx = i - 49152; }
    else return;
    int j  = idx & 7;
    int l  = (idx >> 3) & 63;
    int nt = (idx >> 9) % NT;
    int kt = (idx >> 9) / NT;
    int k = kt * 32 + (l >> 4) * 8 + j;
    int n = nt * 16 + (l & 15);
    int N = NT * 16;
    float v = W[(size_t)k * N + n];
    u16 hi = f2bf(v);
    u16 lo = f2bf(v - bf2f(hi));
    int o = (kt * NT + nt) * 1024 + l * 8 + j;
    dst[o] = hi;
    dst[o + 512] = lo;
}

// ---------------------------------------------------------------------------
// Shared GEMM-chain body (stages A/B/C) used by k_gfm and k_fmfma.
// LDS planes are passed in; A-frag row = lane&15, k-slot = (lane>>4)*8+j;
// C/D: col = lane&15, row = (lane>>4)*4 + reg (m89/m91-verified).
// ---------------------------------------------------------------------------
__device__ __forceinline__ void gemm_chain(
        const float* __restrict__ x0, const u16* __restrict__ wp,
        const float* __restrict__ bc, const float* __restrict__ b1,
        const float* __restrict__ b2, float* __restrict__ out,
        u16* rs_hi, u16* rs_lo, u16* ag_hi, u16* ag_lo,
        u16* hs_hi, u16* hs_lo, int row0, int w, int l) {
    int lr = l & 15;
    int lg = l >> 4;

    // ---- stage A: conv = ag@Wc (32x128); wave w: nt in {2w,2w+1} ----
    {
        f32x4 acc[2][2];
#pragma unroll
        for (int mi = 0; mi < 2; ++mi)
#pragma unroll
            for (int ni = 0; ni < 2; ++ni) acc[mi][ni] = (f32x4){0.f, 0.f, 0.f, 0.f};
#pragma unroll
        for (int kt = 0; kt < 4; ++kt) {
            int ka = kt * 32 + lg * 8;
            s16x8 a0h = *(const s16x8*)(ag_hi + lr * 136 + ka);
            s16x8 a0l = *(const s16x8*)(ag_lo + lr * 136 + ka);
            s16x8 a1h = *(const s16x8*)(ag_hi + (16 + lr) * 136 + ka);
            s16x8 a1l = *(const s16x8*)(ag_lo + (16 + lr) * 136 + ka);
#pragma unroll
            for (int ni = 0; ni < 2; ++ni) {
                int nt = 2 * w + ni;
                const u16* bp = wp + (kt * 8 + nt) * 1024 + l * 8;
                s16x8 bh = *(const s16x8*)(bp);
                s16x8 bl = *(const s16x8*)(bp + 512);
                acc[0][ni] = __builtin_amdgcn_mfma_f32_16x16x32_bf16(a0h, bl, acc[0][ni], 0, 0, 0);
                acc[0][ni] = __builtin_amdgcn_mfma_f32_16x16x32_bf16(a0l, bh, acc[0][ni], 0, 0, 0);
                acc[0][ni] = __builtin_amdgcn_mfma_f32_16x16x32_bf16(a0h, bh, acc[0][ni], 0, 0, 0);
                acc[1][ni] = __builtin_amdgcn_mfma_f32_16x16x32_bf16(a1h, bl, acc[1][ni], 0, 0, 0);
                acc[1][ni] = __builtin_amdgcn_mfma_f32_16x16x32_bf16(a1l, bh, acc[1][ni], 0, 0, 0);
                acc[1][ni] = __builtin_amdgcn_mfma_f32_16x16x32_bf16(a1h, bh, acc[1][ni], 0, 0, 0);
            }
        }
        __syncthreads();   // ag reads done before rs writes / later hs overlay
#pragma unroll
        for (int ni = 0; ni < 2; ++ni) {
            int col = (2 * w + ni) * 16 + lr;
            float bias = bc[col];
#pragma unroll
            for (int mi = 0; mi < 2; ++mi)
#pragma unroll
                for (int r = 0; r < 4; ++r) {
                    int row = mi * 16 + lg * 4 + r;
                    float v = acc[mi][ni][r] + bias;
                    v = fmaxf(v, 0.f) + x0[(size_t)(row0 + row) * Fn + col];
                    u16 h = f2bf(v);
                    rs_hi[row * 136 + col] = h;
                    rs_lo[row * 136 + col] = f2bf(v - bf2f(h));
                }
        }
    }
    __syncthreads();

    // ---- stage B: hs = leaky(rs@W1 + b1) (32x256); nt in {4w..4w+3} ----
    {
        const u16* w1p = wp + 32768;
        f32x4 acc[2][4];
#pragma unroll
        for (int mi = 0; mi < 2; ++mi)
#pragma unroll
            for (int ni = 0; ni < 4; ++ni) acc[mi][ni] = (f32x4){0.f, 0.f, 0.f, 0.f};
#pragma unroll
        for (int kt = 0; kt < 4; ++kt) {
            int ka = kt * 32 + lg * 8;
            s16x8 a0h = *(const s16x8*)(rs_hi + lr * 136 + ka);
            s16x8 a0l = *(const s16x8*)(rs_lo + lr * 136 + ka);
            s16x8 a1h = *(const s16x8*)(rs_hi + (16 + lr) * 136 + ka);
            s16x8 a1l = *(const s16x8*)(rs_lo + (16 + lr) * 136 + ka);
#pragma unroll
            for (int ni = 0; ni < 4; ++ni) {
                int nt = 4 * w + ni;
                const u16* bp = w1p + (kt * 16 + nt) * 1024 + l * 8;
                s16x8 bh = *(const s16x8*)(bp);
                s16x8 bl = *(const s16x8*)(bp + 512);
                acc[0][ni] = __builtin_amdgcn_mfma_f32_16x16x32_bf16(a0h, bl, acc[0][ni], 0, 0, 0);
                acc[0][ni] = __builtin_amdgcn_mfma_f32_16x16x32_bf16(a0l, bh, acc[0][ni], 0, 0, 0);
                acc[0][ni] = __builtin_amdgcn_mfma_f32_16x16x32_bf16(a0h, bh, acc[0][ni], 0, 0, 0);
                acc[1][ni] = __builtin_amdgcn_mfma_f32_16x16x32_bf16(a1h, bl, acc[1][ni], 0, 0, 0);
                acc[1][ni] = __builtin_amdgcn_mfma_f32_16x16x32_bf16(a1l, bh, acc[1][ni], 0, 0, 0);
                acc[1][ni] = __builtin_amdgcn_mfma_f32_16x16x32_bf16(a1h, bh, acc[1][ni], 0, 0, 0);
            }
        }
#pragma unroll
        for (int ni = 0; ni < 4; ++ni) {
            int col = (4 * w + ni) * 16 + lr;
            float bias = b1[col];
#pragma unroll
            for (int mi = 0; mi < 2; ++mi)
#pragma unroll
                for (int r = 0; r < 4; ++r) {
                    int row = mi * 16 + lg * 4 + r;
                    float v = acc[mi][ni][r] + bias;
                    v = v > 0.f ? v : 0.01f * v;
                    u16 h = f2bf(v);
                    hs_hi[row * 264 + col] = h;
                    hs_lo[row * 264 + col] = f2bf(v - bf2f(h));
                }
        }
    }
    __syncthreads();

    // ---- stage C: out = leaky(hs@W2 + b2) (32x256), K=256 ----
    {
        const u16* w2p = wp + 98304;
        f32x4 acc[2][4];
#pragma unroll
        for (int mi = 0; mi < 2; ++mi)
#pragma unroll
            for (int ni = 0; ni < 4; ++ni) acc[mi][ni] = (f32x4){0.f, 0.f, 0.f, 0.f};
#pragma unroll
        for (int kt = 0; kt < 8; ++kt) {
            int ka = kt * 32 + lg * 8;
            s16x8 a0h = *(const s16x8*)(hs_hi + lr * 264 + ka);
            s16x8 a0l = *(const s16x8*)(hs_lo + lr * 264 + ka);
            s16x8 a1h = *(const s16x8*)(hs_hi + (16 + lr) * 264 + ka);
            s16x8 a1l = *(const s16x8*)(hs_lo + (16 + lr) * 264 + ka);
#pragma unroll
            for (int ni = 0; ni < 4; ++ni) {
                int nt = 4 * w + ni;
                const u16* bp = w2p + (kt * 16 + nt) * 1024 + l * 8;
                s16x8 bh = *(const s16x8*)(bp);
                s16x8 bl = *(const s16x8*)(bp + 512);
                acc[0][ni] = __builtin_amdgcn_mfma_f32_16x16x32_bf16(a0h, bl, acc[0][ni], 0, 0, 0);
                acc[0][ni] = __builtin_amdgcn_mfma_f32_16x16x32_bf16(a0l, bh, acc[0][ni], 0, 0, 0);
                acc[0][ni] = __builtin_amdgcn_mfma_f32_16x16x32_bf16(a0h, bh, acc[0][ni], 0, 0, 0);
                acc[1][ni] = __builtin_amdgcn_mfma_f32_16x16x32_bf16(a1h, bl, acc[1][ni], 0, 0, 0);
                acc[1][ni] = __builtin_amdgcn_mfma_f32_16x16x32_bf16(a1l, bh, acc[1][ni], 0, 0, 0);
                acc[1][ni] = __builtin_amdgcn_mfma_f32_16x16x32_bf16(a1h, bh, acc[1][ni], 0, 0, 0);
            }
        }
#pragma unroll
        for (int ni = 0; ni < 4; ++ni) {
            int col = (4 * w + ni) * 16 + lr;
            float bias = b2[col];
#pragma unroll
            for (int mi = 0; mi < 2; ++mi)
#pragma unroll
                for (int r = 0; r < 4; ++r) {
                    int row = mi * 16 + lg * 4 + r;
                    float v = acc[mi][ni][r] + bias;
                    v = v > 0.f ? v : 0.01f * v;
                    out[((size_t)(row0 + row) << 8) + col] = v;
                }
        }
    }
}

// ---------------------------------------------------------------------------
// Tier-3 fused kernel: gather (into LDS) + GEMM chain. 2500 blocks.
// XCD-bijective swizzle (q=312, r=4): blocks with blockIdx%8==x form one
// contiguous row chunk -> each XCD's L2 holds ~one graph's 2.56 MB f16 table.
// ---------------------------------------------------------------------------
__device__ __forceinline__ void g_edge_h(const __half* __restrict__ x0h, int s,
                                         float w, int lane, float& ax, float& ay) {
    __half2 h = *(const __half2*)(x0h + ((size_t)s << 7) + 2 * lane);
    float2 v = __half22float2(h);
    ax = fmaf(w, v.x, ax);
    ay = fmaf(w, v.y, ay);
}

__global__ __launch_bounds__(256, 3) void k_gfm(
        const float* __restrict__ x0, const __half* __restrict__ x0h,
        const float* __restrict__ dinv,
        const int* __restrict__ row_start, const int* __restrict__ row_end,
        const int* __restrict__ elist, const float* __restrict__ wl,
        const u16* __restrict__ wp,
        const float* __restrict__ bc, const float* __restrict__ b1,
        const float* __restrict__ b2, float* out) {
    __shared__ __align__(16) u16 sm[25600];
    u16* rs_hi = sm;              // [32][136]
    u16* rs_lo = sm + 4352;
    u16* ag_hi = sm + 8704;       // [32][136]
    u16* ag_lo = sm + 13056;
    u16* hs_hi = sm + 8704;       // [32][264] overlays ag (dead after stage A)
    u16* hs_lo = sm + 17152;

    // bijective XCD chunk swizzle: 2500 = 4*313 + 4*312
    int xcd = blockIdx.x & 7, ii = blockIdx.x >> 3;
    int wg = (xcd < 4 ? xcd * 313 : 1252 + (xcd - 4) * 312) + ii;
    int row0 = wg * TM;

    int t = threadIdx.x;
    int w = t >> 6;               // wave 0..3
    int l = t & 63;

    // ---- phase 0: each wave gathers 8 rows into split-bf16 LDS planes ----
#pragma unroll 1
    for (int rr = 0; rr < 8; ++rr) {
        int r = w * 8 + rr;
        int wid = row0 + r;
        int rs = row_start[wid], re = row_end[wid];
        float ax = 0.f, ay = 0.f;
        int j = rs;
        while (j < re && (j & 3)) { g_edge_h(x0h, elist[j], wl[j], l, ax, ay); ++j; }
        for (; j + 8 <= re; j += 8) {
            int4   ea = *(const int4*)(elist + j);
            int4   eb = *(const int4*)(elist + j + 4);
            float4 wa = *(const float4*)(wl + j);
            float4 wb = *(const float4*)(wl + j + 4);
            g_edge_h(x0h, ea.x, wa.x, l, ax, ay);
            g_edge_h(x0h, ea.y, wa.y, l, ax, ay);
            g_edge_h(x0h, ea.z, wa.z, l, ax, ay);
            g_edge_h(x0h, ea.w, wa.w, l, ax, ay);
            g_edge_h(x0h, eb.x, wb.x, l, ax, ay);
            g_edge_h(x0h, eb.y, wb.y, l, ax, ay);
            g_edge_h(x0h, eb.z, wb.z, l, ax, ay);
            g_edge_h(x0h, eb.w, wb.w, l, ax, ay);
        }
        if (j + 4 <= re) {
            int4   ea = *(const int4*)(elist + j);
            float4 wa = *(const float4*)(wl + j);
            g_edge_h(x0h, ea.x, wa.x, l, ax, ay);
            g_edge_h(x0h, ea.y, wa.y, l, ax, ay);
            g_edge_h(x0h, ea.z, wa.z, l, ax, ay);
            g_edge_h(x0h, ea.w, wa.w, l, ax, ay);
            j += 4;
        }
        for (; j < re; ++j) g_edge_h(x0h, elist[j], wl[j], l, ax, ay);
        float wd = dinv[wid];
        g_edge_h(x0h, wid, wd, l, ax, ay);   // self-loop
        float sx = wd * ax, sy = wd * ay;
        u16 h0 = f2bf(sx), h1 = f2bf(sy);
        u16 l0 = f2bf(sx - bf2f(h0)), l1 = f2bf(sy - bf2f(h1));
        ((unsigned*)ag_hi)[r * 68 + l] = (unsigned)h0 | ((unsigned)h1 << 16);
        ((unsigned*)ag_lo)[r * 68 + l] = (unsigned)l0 | ((unsigned)l1 << 16);
    }
    __syncthreads();

    gemm_chain(x0, wp, bc, b1, b2, out,
               rs_hi, rs_lo, ag_hi, ag_lo, hs_hi, hs_lo, row0, w, l);
}

// ---------------------------------------------------------------------------
// Tier-2 standalone gather (AGG planes + f16 table live inside out rows).
// XCD swizzle: 20,000 blocks = 8 * 2500; chunk per XCD = exactly one graph.
// ---------------------------------------------------------------------------
__device__ __forceinline__ void g_edge(const char* __restrict__ outc, int s,
                                       float w, int lane, float& ax, float& ay) {
    __half2 h = *(const __half2*)(outc + ((size_t)s << 10) + 512 + 4 * lane);
    float2 v = __half22float2(h);
    ax = fmaf(w, v.x, ax);
    ay = fmaf(w, v.y, ay);
}

__global__ __launch_bounds__(256) void k_gather(
        const float* __restrict__ dinv,
        const int* __restrict__ row_start, const int* __restrict__ row_end,
        const int* __restrict__ elist, const float* __restrict__ wl,
        float* __restrict__ out) {
    int sb = (blockIdx.x & 7) * 2500 + (blockIdx.x >> 3);   // XCD chunking
    int wid = ((sb * 256 + threadIdx.x) >> 6);
    int lane = threadIdx.x & 63;
    if (wid >= NROW) return;
    const char* outc = (const char*)out;
    int rs = row_start[wid], re = row_end[wid];
    float ax = 0.f, ay = 0.f;
    int j = rs;
    if (wl) {
        while (j < re && (j & 3)) { g_edge(outc, elist[j], wl[j], lane, ax, ay); ++j; }
        for (; j + 8 <= re; j += 8) {
            int4   ea = *(const int4*)(elist + j);
            int4   eb = *(const int4*)(elist + j + 4);
            float4 wa = *(const float4*)(wl + j);
            float4 wb = *(const float4*)(wl + j + 4);
            g_edge(outc, ea.x, wa.x, lane, ax, ay);
            g_edge(outc, ea.y, wa.y, lane, ax, ay);
            g_edge(outc, ea.z, wa.z, lane, ax, ay);
            g_edge(outc, ea.w, wa.w, lane, ax, ay);
            g_edge(outc, eb.x, wb.x, lane, ax, ay);
            g_edge(outc, eb.y, wb.y, lane, ax, ay);
            g_edge(outc, eb.z, wb.z, lane, ax, ay);
            g_edge(outc, eb.w, wb.w, lane, ax, ay);
        }
        if (j + 4 <= re) {
            int4   ea = *(const int4*)(elist + j);
            float4 wa = *(const float4*)(wl + j);
            g_edge(outc, ea.x, wa.x, lane, ax, ay);
            g_edge(outc, ea.y, wa.y, lane, ax, ay);
            g_edge(outc, ea.z, wa.z, lane, ax, ay);
            g_edge(outc, ea.w, wa.w, lane, ax, ay);
            j += 4;
        }
        for (; j < re; ++j) g_edge(outc, elist[j], wl[j], lane, ax, ay);
    } else {
        for (; j + 4 <= re; j += 4) {
            int s0 = elist[j], s1 = elist[j + 1], s2 = elist[j + 2], s3 = elist[j + 3];
            float w0 = dinv[s0], w1 = dinv[s1], w2 = dinv[s2], w3 = dinv[s3];
            g_edge(outc, s0, w0, lane, ax, ay);
            g_edge(outc, s1, w1, lane, ax, ay);
            g_edge(outc, s2, w2, lane, ax, ay);
            g_edge(outc, s3, w3, lane, ax, ay);
        }
        for (; j < re; ++j) {
            int s = elist[j];
            g_edge(outc, s, dinv[s], lane, ax, ay);
        }
    }
    float wd = dinv[wid];
    g_edge(outc, wid, wd, lane, ax, ay);
    float sx = wd * ax, sy = wd * ay;
    u16 h0 = f2bf(sx), h1 = f2bf(sy);
    u16 l0 = f2bf(sx - bf2f(h0)), l1 = f2bf(sy - bf2f(h1));
    unsigned* orow = (unsigned*)(out + ((size_t)wid << 8));
    orow[lane]      = (unsigned)h0 | ((unsigned)h1 << 16);
    orow[64 + lane] = (unsigned)l0 | ((unsigned)l1 << 16);
}

// Tier-2 GEMM kernel: copy packed AGG planes from out, then chain.
__global__ __launch_bounds__(256, 3) void k_fmfma(
        const float* __restrict__ x0, const u16* __restrict__ wp,
        const float* __restrict__ bc, const float* __restrict__ b1,
        const float* __restrict__ b2, float* out) {
    __shared__ __align__(16) u16 sm[25600];
    u16* rs_hi = sm;
    u16* rs_lo = sm + 4352;
    u16* ag_hi = sm + 8704;
    u16* ag_lo = sm + 13056;
    u16* hs_hi = sm + 8704;
    u16* hs_lo = sm + 17152;

    int row0 = blockIdx.x * TM;
    int t = threadIdx.x;
    int w = t >> 6;
    int l = t & 63;

#pragma unroll
    for (int it = 0; it < 4; ++it) {
        int idx = it * 256 + t;
        int r = idx >> 5, q = idx & 31;
        uint4 v = *(const uint4*)((const char*)out +
                                  ((size_t)(row0 + r) << 10) + (q << 4));
        u16* dst = (q < 16) ? (ag_hi + r * 136 + (q << 3))
                            : (ag_lo + r * 136 + ((q - 16) << 3));
        *(uint4*)dst = v;
    }
    __syncthreads();

    gemm_chain(x0, wp, bc, b1, b2, out,
               rs_hi, rs_lo, ag_hi, ag_lo, hs_hi, hs_lo, row0, w, l);
}

// ---------------------------------------------------------------------------
// Full fallback (tiny workspace): float degree + atomic scatter + f32 fused.
// ---------------------------------------------------------------------------
__global__ void k_canary(float* out) {
    if (threadIdx.x == 0 && blockIdx.x == 0) out[4] = 1000.0f;
}
__global__ void k_deg_init(float* __restrict__ deg) {
    int i = blockIdx.x * blockDim.x + threadIdx.x;
    if (i < NROW) deg[i] = 1.0f;
}
__global__ void k_deg_count(const int* __restrict__ e, float* __restrict__ deg) {
    bool i64 = edge_is_i64(e);
    int i = blockIdx.x * blockDim.x + threadIdx.x;
    if (i >= NEDGE) return;
    int b = i / En, k = i - b * En;
    int dst = eidx(e, (long long)(b * 2 + 1) * En + k, i64);
    if ((unsigned)dst < Nn) atomicAdd(&deg[b * Nn + dst], 1.0f);
}
__global__ void k_dinv(float* __restrict__ deg) {
    int i = blockIdx.x * blockDim.x + threadIdx.x;
    if (i < NROW) deg[i] = rsqrtf(deg[i]);
}
__global__ void k_agg_init(const float* __restrict__ x0,
                           const float* __restrict__ dinv,
                           float* __restrict__ out) {
    int i = blockIdx.x * blockDim.x + threadIdx.x;
    if (i >= NROW * Fn) return;
    int r = i >> 7;
    int c = i & 127;
    float dv = dinv[r];
    out[((size_t)r << 8) + c] = dv * dv * x0[i];
}
__global__ void k_scatter(const int* __restrict__ e,
                          const float* __restrict__ dinv,
                          const float* __restrict__ x0,
                          float* __restrict__ out) {
    bool i64 = edge_is_i64(e);
    long long gid = (long long)blockIdx.x * blockDim.x + threadIdx.x;
    int eid = (int)(gid >> 6);
    int lane = (int)(gid & 63);
    if (eid >= NEDGE) return;
    int b = eid / En, k = eid - b * En;
    int src = eidx(e, (long long)(b * 2) * En + k, i64);
    int dst = eidx(e, (long long)(b * 2 + 1) * En + k, i64);
    if ((unsigned)src >= Nn || (unsigned)dst >= Nn) return;
    float nrm = dinv[b * Nn + src] * dinv[b * Nn + dst];
    const float2 vf =
        *(const float2*)(x0 + ((size_t)(b * Nn + src) << 7) + 2 * lane);
    float* p = out + ((size_t)(b * Nn + dst) << 8) + 2 * lane;
    atomicAdd(p, nrm * vf.x);
    atomicAdd(p + 1, nrm * vf.y);
}

__global__ __launch_bounds__(256, 3) void k_fused(
        const float* __restrict__ x0,
        const float* __restrict__ Wc, const float* __restrict__ bc,
        const float* __restrict__ W1, const float* __restrict__ b1,
        const float* __restrict__ W2, const float* __restrict__ b2,
        float* out) {
    __shared__ float smem[12352];
    float (*rs)[Fn + 1] = (float (*)[Fn + 1])smem;
    float (*ag)[Fn + 1] = (float (*)[Fn + 1])(smem + 4128);
    float (*hs)[Hn + 1] = (float (*)[Hn + 1])(smem + 4128);

    int row0 = blockIdx.x * TM;
    int t = threadIdx.x;
    int tx = t & 31;
    int ty = t >> 5;
    int ra = ty * 4;

    for (int i = t; i < TM * Fn; i += 256) {
        int r = i >> 7, c = i & 127;
        ag[r][c] = out[((size_t)(row0 + r) << 8) + c];
    }
    __syncthreads();
    {
        float acc[4][4] = {};
#pragma unroll 4
        for (int k = 0; k < Fn; ++k) {
            float a0 = ag[ra + 0][k], a1 = ag[ra + 1][k],
                  a2 = ag[ra + 2][k], a3 = ag[ra + 3][k];
            const float4 b = *(const float4*)(Wc + k * Fn + tx * 4);
            acc[0][0] = fmaf(a0, b.x, acc[0][0]); acc[0][1] = fmaf(a0, b.y, acc[0][1]);
            acc[0][2] = fmaf(a0, b.z, acc[0][2]); acc[0][3] = fmaf(a0, b.w, acc[0][3]);
            acc[1][0] = fmaf(a1, b.x, acc[1][0]); acc[1][1] = fmaf(a1, b.y, acc[1][1]);
            acc[1][2] = fmaf(a1, b.z, acc[1][2]); acc[1][3] = fmaf(a1, b.w, acc[1][3]);
            acc[2][0] = fmaf(a2, b.x, acc[2][0]); acc[2][1] = fmaf(a2, b.y, acc[2][1]);
            acc[2][2] = fmaf(a2, b.z, acc[2][2]); acc[2][3] = fmaf(a2, b.w, acc[2][3]);
            acc[3][0] = fmaf(a3, b.x, acc[3][0]); acc[3][1] = fmaf(a3, b.y, acc[3][1]);
            acc[3][2] = fmaf(a3, b.z, acc[3][2]); acc[3][3] = fmaf(a3, b.w, acc[3][3]);
        }
        const float4 bcv = *(const float4*)(bc + tx * 4);
        __syncthreads();
#pragma unroll
        for (int i = 0; i < 4; ++i) {
            const float4 xv =
                *(const float4*)(x0 + (size_t)(row0 + ra + i) * Fn + tx * 4);
            rs[ra + i][tx * 4 + 0] = fmaxf(acc[i][0] + bcv.x, 0.f) + xv.x;
            rs[ra + i][tx * 4 + 1] = fmaxf(acc[i][1] + bcv.y, 0.f) + xv.y;
            rs[ra + i][tx * 4 + 2] = fmaxf(acc[i][2] + bcv.z, 0.f) + xv.z;
            rs[ra + i][tx * 4 + 3] = fmaxf(acc[i][3] + bcv.w, 0.f) + xv.w;
        }
    }
    __syncthreads();
    {
        float acc[4][8] = {};
#pragma unroll 2
        for (int k = 0; k < Fn; ++k) {
            float a0 = rs[ra + 0][k], a1 = rs[ra + 1][k],
                  a2 = rs[ra + 2][k], a3 = rs[ra + 3][k];
            const float4 p0 = *(const float4*)(W1 + k * Hn + tx * 8);
            const float4 p1 = *(const float4*)(W1 + k * Hn + tx * 8 + 4);
#pragma unroll
            for (int i = 0; i < 4; ++i) {
                float a = (i == 0) ? a0 : (i == 1) ? a1 : (i == 2) ? a2 : a3;
                acc[i][0] = fmaf(a, p0.x, acc[i][0]); acc[i][1] = fmaf(a, p0.y, acc[i][1]);
                acc[i][2] = fmaf(a, p0.z, acc[i][2]); acc[i][3] = fmaf(a, p0.w, acc[i][3]);
                acc[i][4] = fmaf(a, p1.x, acc[i][4]); acc[i][5] = fmaf(a, p1.y, acc[i][5]);
                acc[i][6] = fmaf(a, p1.z, acc[i][6]); acc[i][7] = fmaf(a, p1.w, acc[i][7]);
            }
        }
        const float4 b1a = *(const float4*)(b1 + tx * 8);
        const float4 b1b = *(const float4*)(b1 + tx * 8 + 4);
        float bias[8] = {b1a.x, b1a.y, b1a.z, b1a.w, b1b.x, b1b.y, b1b.z, b1b.w};
#pragma unroll
        for (int i = 0; i < 4; ++i)
#pragma unroll
            for (int j = 0; j < 8; ++j) {
                float h = acc[i][j] + bias[j];
                hs[ra + i][tx * 8 + j] = h > 0.f ? h : 0.01f * h;
            }
    }
    __syncthreads();
    {
        float acc[4][8] = {};
#pragma unroll 2
        for (int k = 0; k < Hn; ++k) {
            float a0 = hs[ra + 0][k], a1 = hs[ra + 1][k],
                  a2 = hs[ra + 2][k], a3 = hs[ra + 3][k];
            const float4 p0 = *(const float4*)(W2 + k * Hn + tx * 8);
            const float4 p1 = *(const float4*)(W2 + k * Hn + tx * 8 + 4);
#pragma unroll
            for (int i = 0; i < 4; ++i) {
                float a = (i == 0) ? a0 : (i == 1) ? a1 : (i == 2) ? a2 : a3;
                acc[i][0] = fmaf(a, p0.x, acc[i][0]); acc[i][1] = fmaf(a, p0.y, acc[i][1]);
                acc[i][2] = fmaf(a, p0.z, acc[i][2]); acc[i][3] = fmaf(a, p0.w, acc[i][3]);
                acc[i][4] = fmaf(a, p1.x, acc[i][4]); acc[i][5] = fmaf(a, p1.y, acc[i][5]);
                acc[i][6] = fmaf(a, p1.z, acc[i][6]); acc[i][7] = fmaf(a, p1.w, acc[i][7]);
            }
        }
        const float4 b2a = *(const float4*)(b2 + tx * 8);
        const float4 b2b = *(const float4*)(b2 + tx * 8 + 4);
        float bias[8] = {b2a.x, b2a.y, b2a.z, b2a.w, b2b.x, b2b.y, b2b.z, b2b.w};
#pragma unroll
        for (int i = 0; i < 4; ++i) {
            float o[8];
#pragma unroll
            for (int j = 0; j < 8; ++j) {
                float v = acc[i][j] + bias[j];
                o[j] = v > 0.f ? v : 0.01f * v;
            }
            float* dst = out + ((size_t)(row0 + ra + i) << 8) + tx * 8;
            *(float4*)(dst)     = make_float4(o[0], o[1], o[2], o[3]);
            *(float4*)(dst + 4) = make_float4(o[4], o[5], o[6], o[7]);
        }
    }
}

// ---------------------------------------------------------------------------
extern "C" void kernel_launch(void* const* d_in, const int* in_sizes, int n_in,
                              void* d_out, int out_size, void* d_ws, size_t ws_size,
                              hipStream_t stream) {
    const float* x0 = (const float*)d_in[0];
    const int*   ed = (const int*)d_in[1];
    const float* Wc = (const float*)d_in[2];
    const float* bc = (const float*)d_in[3];
    const float* W1 = (const float*)d_in[4];
    const float* b1 = (const float*)d_in[5];
    const float* W2 = (const float*)d_in[6];
    const float* b2 = (const float*)d_in[7];

    float* out = (float*)d_out;
    int*   wsi = (int*)d_ws;
    float* wsf = (float*)d_ws;

    bool t3 = ws_size >= WS3_BYTES;
    bool t2 = ws_size >= WS2_BYTES;
    bool t1 = ws_size >= WS1_BYTES;

    if (t1 || t2 || t3) {
        int*   degi      = wsi;                 // -> dinv (f32) after scan3
        float* dinv      = wsf;
        int*   row_start = wsi + OFF_RS;
        int*   cursor    = wsi + OFF_CUR;
        int*   bsum      = wsi + OFF_BS;
        int*   boff      = wsi + OFF_BO;
        int*   elist     = wsi + OFF_EL;
        float* wl        = (t2 || t3) ? (wsf + OFF_WL) : nullptr;
        u16*   wp        = (u16*)(wsi + ((t2 || t3) ? WS2_INTS : WS1_INTS));
        __half* x0h      = (__half*)((char*)d_ws + WS2_BYTES);

        if (t3) {
            k_init3<<<10000, 256, 0, stream>>>(degi, x0h, x0, out);
        } else {
            k_init<<<313, 256, 0, stream>>>(degi, out);
            k_xh<<<10000, 256, 0, stream>>>(x0, out);
        }
        k_deg_count_i<<<(NEDGE + 255) / 256, 256, 0, stream>>>(ed, degi);
        k_scan1<<<313, 256, 0, stream>>>(degi, row_start, bsum);
        k_scan2<<<1, 512, 0, stream>>>(bsum, boff, row_start);
        k_scan3<<<313, 256, 0, stream>>>(degi, dinv, row_start, boff, cursor);
        k_bin<<<(NEDGE + 255) / 256, 256, 0, stream>>>(ed, dinv, cursor, elist, wl);
        k_wpack<<<448, 256, 0, stream>>>(Wc, W1, W2, wp);
        if (t3) {
            k_gfm<<<NROW / TM, 256, 0, stream>>>(
                x0, x0h, dinv, row_start, cursor, elist, wl, wp, bc, b1, b2, out);
        } else {
            k_gather<<<NROW / 4, 256, 0, stream>>>(
                dinv, row_start, cursor, elist, wl, out);
            k_fmfma<<<NROW / TM, 256, 0, stream>>>(x0, wp, bc, b1, b2, out);
        }
    } else {
        float* deg = wsf;
        k_canary<<<1, 64, 0, stream>>>(out);
        k_deg_init<<<(NROW + 255) / 256, 256, 0, stream>>>(deg);
        k_deg_count<<<(NEDGE + 255) / 256, 256, 0, stream>>>(ed, deg);
        k_dinv<<<(NROW + 255) / 256, 256, 0, stream>>>(deg);
        k_agg_init<<<(NROW * Fn + 255) / 256, 256, 0, stream>>>(x0, deg, out);
        long long sthreads = (long long)NEDGE * 64;
        k_scatter<<<(int)((sthreads + 255) / 256), 256, 0, stream>>>(ed, deg, x0, out);
        k_fused<<<NROW / TM, 256, 0, stream>>>(x0, Wc, bc, W1, b1, W2, b2, out);
    }
}

// Round 5
// 384.668 us; speedup vs baseline: 1.0819x; 1.0819x over previous
//
#include <hip/hip_runtime.h>
#include <hip/hip_bf16.h>
#include <hip/hip_fp16.h>

// Problem constants: B=8, N=10000, E=160000, F=128, H=256
#define Bn 8
#define Nn 10000
#define En 160000
#define Fn 128
#define Hn 256
#define NROW (Bn * Nn)     // 80,000
#define NEDGE (Bn * En)    // 1,280,000
#define TM 32              // rows per block in fused epilogue

// Workspace layout (ints):
//   [0,80000)            deg (int) -> dinv (f32) after k_scan3
//   [80000,160001)       row_start
//   [160004,240004)      cursor
//   [240004,240317)      bsum (313)
//   [240320,240832)      boff (512)
//   [240832,1520832)     elist (global src per edge, CSR order)
//   [1520832,2800832)    wlist (dinv[src] per edge)  [tier >= 2]
//   then 458,752 B packed split-bf16 weights (u16), 16B-aligned
//   then (tier 3) 20,480,000 B x0 as f16 [NROW][128].
// Tier-2 out row layout (1024 B): [0,256)=AGG hi bf16, [256,512)=AGG lo,
//   [512,768)=x0 f16 copy. Tier-3: gather reads x0h table, writes AGG
//   planes to out[0,512); k_fmfma overwrites all 1024 B in stage C.
// R5: k_gfm (fused gather+GEMM) REVERTED — gather behind the GEMM's
// 3-block/CU occupancy exposed L2 latency (m: MfmaUtil 26->13, +30us).
// Split keeps gather at ~80% occupancy; x0h table + XCD chunking kept.
#define OFF_RS   80000
#define OFF_CUR  160004
#define OFF_BS   240004
#define OFF_BO   240320
#define OFF_EL   240832
#define OFF_WL   1520832
#define WS1_INTS 1520832
#define WS2_INTS 2800832
#define WP_BYTES 458752
#define X0H_BYTES ((size_t)NROW * Fn * 2)             // 20,480,000
#define WS1_BYTES ((size_t)WS1_INTS * 4 + WP_BYTES)   // 6,542,080
#define WS2_BYTES ((size_t)WS2_INTS * 4 + WP_BYTES)   // 11,662,080
#define WS3_BYTES (WS2_BYTES + X0H_BYTES)             // 32,142,080

typedef unsigned short u16;
typedef __attribute__((ext_vector_type(8))) short s16x8;
typedef __attribute__((ext_vector_type(4))) float f32x4;

__device__ __forceinline__ u16 f2bf(float x) {           // RNE f32->bf16
    unsigned u = __float_as_uint(x);
    u += 0x7FFF + ((u >> 16) & 1);
    return (u16)(u >> 16);
}
__device__ __forceinline__ float bf2f(u16 h) {
    return __uint_as_float((unsigned)h << 16);
}

__device__ __forceinline__ bool edge_is_i64(const int* e) {
    return e[1] == 0 && e[3] == 0;
}
__device__ __forceinline__ int eidx(const int* e, long long i, bool i64) {
    return i64 ? e[2 * i] : e[i];
}

// ---------------------------------------------------------------------------
// Tier-3 init: deg=1, canary poison, x0 -> f16 table in workspace.
// ---------------------------------------------------------------------------
__global__ void k_init3(int* __restrict__ deg, __half* __restrict__ x0h,
                        const float* __restrict__ x0, float* __restrict__ out) {
    int i = blockIdx.x * 256 + threadIdx.x;     // < NROW*32
    if (i >= NROW * 32) return;
    if (i < NROW) deg[i] = 1;
    if (i == 0) out[4] = 1000.0f;               // erased by k_gather3 AGG write
    int r = i >> 5, g = i & 31;
    float4 v = *(const float4*)(x0 + ((size_t)r << 7) + (g << 2));
    __half2 a = __floats2half2_rn(v.x, v.y);
    __half2 b = __floats2half2_rn(v.z, v.w);
    uint2 u;
    u.x = *(unsigned*)&a;
    u.y = *(unsigned*)&b;
    *(uint2*)((char*)x0h + ((size_t)r << 8) + (g << 3)) = u;
}

// Tier-2 init: deg=1 + canary.
__global__ void k_init(int* __restrict__ deg, float* __restrict__ out) {
    int i = blockIdx.x * blockDim.x + threadIdx.x;
    if (i < NROW) deg[i] = 1;
    if (i == 0) out[4] = 1000.0f;
}

// Tier-2: x0 -> f16 into out row bytes [512,768).
__global__ void k_xh(const float* __restrict__ x0, float* __restrict__ out) {
    int i = blockIdx.x * 256 + threadIdx.x;
    if (i >= NROW * 32) return;
    int r = i >> 5, g = i & 31;
    float4 v = *(const float4*)(x0 + ((size_t)r << 7) + (g << 2));
    __half2 a = __floats2half2_rn(v.x, v.y);
    __half2 b = __floats2half2_rn(v.z, v.w);
    uint2 u;
    u.x = *(unsigned*)&a;
    u.y = *(unsigned*)&b;
    *(uint2*)((char*)out + ((size_t)r << 10) + 512 + (g << 3)) = u;
}

__global__ void k_deg_count_i(const int* __restrict__ e, int* __restrict__ deg) {
    bool i64 = edge_is_i64(e);
    int i = blockIdx.x * blockDim.x + threadIdx.x;
    if (i >= NEDGE) return;
    int b = i / En, k = i - b * En;
    int dst = eidx(e, (long long)(b * 2 + 1) * En + k, i64);
    if ((unsigned)dst < Nn) atomicAdd(&deg[b * Nn + dst], 1);
}

// ---------------------------------------------------------------------------
// Exclusive scan of in-degree over 80,000 rows, 3 kernels.
// ---------------------------------------------------------------------------
__global__ void k_scan1(const int* __restrict__ deg,
                        int* __restrict__ row_start, int* __restrict__ bsum) {
    __shared__ int s[256];
    int i = blockIdx.x * 256 + threadIdx.x;
    int v = (i < NROW) ? (deg[i] - 1) : 0;
    s[threadIdx.x] = v;
    __syncthreads();
    for (int off = 1; off < 256; off <<= 1) {
        int t = (threadIdx.x >= off) ? s[threadIdx.x - off] : 0;
        __syncthreads();
        s[threadIdx.x] += t;
        __syncthreads();
    }
    if (i < NROW) row_start[i] = s[threadIdx.x] - v;
    if (threadIdx.x == 255) bsum[blockIdx.x] = s[255];
}

__global__ void k_scan2(const int* __restrict__ bsum, int* __restrict__ boff,
                        int* __restrict__ row_start) {
    __shared__ int s[512];
    int t = threadIdx.x;
    int v = (t < 313) ? bsum[t] : 0;
    s[t] = v;
    __syncthreads();
    for (int off = 1; off < 512; off <<= 1) {
        int u = (t >= off) ? s[t - off] : 0;
        __syncthreads();
        s[t] += u;
        __syncthreads();
    }
    boff[t] = s[t] - v;
    if (t == 511) row_start[NROW] = s[511];
}

__global__ void k_scan3(int* __restrict__ degi, float* __restrict__ dinvf,
                        int* __restrict__ row_start,
                        const int* __restrict__ boff, int* __restrict__ cursor) {
    int i = blockIdx.x * blockDim.x + threadIdx.x;
    if (i >= NROW) return;
    int v = row_start[i] + boff[i >> 8];
    row_start[i] = v;
    cursor[i] = v;
    float d = (float)degi[i];
    dinvf[i] = rsqrtf(d);
}

// ---------------------------------------------------------------------------
// Counting-sort edges by destination; optionally materialize weights.
// ---------------------------------------------------------------------------
__global__ void k_bin(const int* __restrict__ e, const float* __restrict__ dinv,
                      int* __restrict__ cursor, int* __restrict__ elist,
                      float* __restrict__ wl) {
    bool i64 = edge_is_i64(e);
    int i = blockIdx.x * blockDim.x + threadIdx.x;
    if (i >= NEDGE) return;
    int b = i / En, k = i - b * En;
    int src = eidx(e, (long long)(b * 2) * En + k, i64);
    int dst = eidx(e, (long long)(b * 2 + 1) * En + k, i64);
    if ((unsigned)src >= Nn || (unsigned)dst >= Nn) return;
    int gsrc = b * Nn + src;
    int pos = atomicAdd(&cursor[b * Nn + dst], 1);
    elist[pos] = gsrc;
    if (wl) wl[pos] = dinv[gsrc];
}

// ---------------------------------------------------------------------------
// Weight pre-split + pre-swizzle into MFMA B-fragment order.
// Per weight: [kt][nt][h(hi/lo)][lane 64][8 slots] of bf16 (u16).
// k-map: k = kt*32 + (l>>4)*8 + j (same map as A-frags).
// Regions (u16): Wc @0 (32768), W1 @32768 (65536), W2 @98304 (131072).
// ---------------------------------------------------------------------------
__global__ void k_wpack(const float* __restrict__ Wc, const float* __restrict__ W1,
                        const float* __restrict__ W2, u16* __restrict__ wp) {
    int i = blockIdx.x * 256 + threadIdx.x;
    const float* W; u16* dst; int NT, idx;
    if (i < 16384)       { W = Wc; dst = wp;         NT = 8;  idx = i; }
    else if (i < 49152)  { W = W1; dst = wp + 32768; NT = 16; idx = i - 16384; }
    else if (i < 114688) { W = W2; dst = wp + 98304; NT = 16; idx = i - 49152; }
    else return;
    int j  = idx & 7;
    int l  = (idx >> 3) & 63;
    int nt = (idx >> 9) % NT;
    int kt = (idx >> 9) / NT;
    int k = kt * 32 + (l >> 4) * 8 + j;
    int n = nt * 16 + (l & 15);
    int N = NT * 16;
    float v = W[(size_t)k * N + n];
    u16 hi = f2bf(v);
    u16 lo = f2bf(v - bf2f(hi));
    int o = (kt * NT + nt) * 1024 + l * 8 + j;
    dst[o] = hi;
    dst[o + 512] = lo;
}

// ---------------------------------------------------------------------------
// Tier-3 standalone gather: one wave per row, 2 cols/lane, zero LDS (full
// occupancy hides L2 latency — the R4 fusion lesson). Reads the contiguous
// f16 x0h table (2.56 MB/graph, XCD-L2-resident via chunking); writes AGG
// as packed bf16 hi/lo planes into out[0,512).
// ---------------------------------------------------------------------------
__device__ __forceinline__ void g_edge_h(const __half* __restrict__ x0h, int s,
                                         float w, int lane, float& ax, float& ay) {
    __half2 h = *(const __half2*)(x0h + ((size_t)s << 7) + 2 * lane);
    float2 v = __half22float2(h);
    ax = fmaf(w, v.x, ax);
    ay = fmaf(w, v.y, ay);
}

__global__ __launch_bounds__(256) void k_gather3(
        const __half* __restrict__ x0h, const float* __restrict__ dinv,
        const int* __restrict__ row_start, const int* __restrict__ row_end,
        const int* __restrict__ elist, const float* __restrict__ wl,
        float* __restrict__ out) {
    // XCD chunking: 20,000 blocks = 8 * 2500; chunk per XCD = one graph.
    int sb = (blockIdx.x & 7) * 2500 + (blockIdx.x >> 3);
    int wid = ((sb * 256 + (int)threadIdx.x) >> 6);
    int lane = threadIdx.x & 63;
    if (wid >= NROW) return;
    int rs = row_start[wid], re = row_end[wid];
    float wd = dinv[wid];
    float ax = 0.f, ay = 0.f;
    int j = rs;
    while (j < re && (j & 3)) { g_edge_h(x0h, elist[j], wl[j], lane, ax, ay); ++j; }
    for (; j + 8 <= re; j += 8) {
        int4   ea = *(const int4*)(elist + j);
        int4   eb = *(const int4*)(elist + j + 4);
        float4 wa = *(const float4*)(wl + j);
        float4 wb = *(const float4*)(wl + j + 4);
        g_edge_h(x0h, ea.x, wa.x, lane, ax, ay);
        g_edge_h(x0h, ea.y, wa.y, lane, ax, ay);
        g_edge_h(x0h, ea.z, wa.z, lane, ax, ay);
        g_edge_h(x0h, ea.w, wa.w, lane, ax, ay);
        g_edge_h(x0h, eb.x, wb.x, lane, ax, ay);
        g_edge_h(x0h, eb.y, wb.y, lane, ax, ay);
        g_edge_h(x0h, eb.z, wb.z, lane, ax, ay);
        g_edge_h(x0h, eb.w, wb.w, lane, ax, ay);
    }
    if (j + 4 <= re) {
        int4   ea = *(const int4*)(elist + j);
        float4 wa = *(const float4*)(wl + j);
        g_edge_h(x0h, ea.x, wa.x, lane, ax, ay);
        g_edge_h(x0h, ea.y, wa.y, lane, ax, ay);
        g_edge_h(x0h, ea.z, wa.z, lane, ax, ay);
        g_edge_h(x0h, ea.w, wa.w, lane, ax, ay);
        j += 4;
    }
    for (; j < re; ++j) g_edge_h(x0h, elist[j], wl[j], lane, ax, ay);
    g_edge_h(x0h, wid, wd, lane, ax, ay);       // self-loop
    float sx = wd * ax, sy = wd * ay;
    u16 h0 = f2bf(sx), h1 = f2bf(sy);
    u16 l0 = f2bf(sx - bf2f(h0)), l1 = f2bf(sy - bf2f(h1));
    unsigned* orow = (unsigned*)(out + ((size_t)wid << 8));
    orow[lane]      = (unsigned)h0 | ((unsigned)h1 << 16);
    orow[64 + lane] = (unsigned)l0 | ((unsigned)l1 << 16);
}

// ---------------------------------------------------------------------------
// Shared GEMM-chain body (stages A/B/C).
// A-frag: row = lane&15, k-slot = (lane>>4)*8+j; C/D: col = lane&15,
// row = (lane>>4)*4 + reg (m89/m91-verified).
// ---------------------------------------------------------------------------
__device__ __forceinline__ void gemm_chain(
        const float* __restrict__ x0, const u16* __restrict__ wp,
        const float* __restrict__ bc, const float* __restrict__ b1,
        const float* __restrict__ b2, float* __restrict__ out,
        u16* rs_hi, u16* rs_lo, u16* ag_hi, u16* ag_lo,
        u16* hs_hi, u16* hs_lo, int row0, int w, int l) {
    int lr = l & 15;
    int lg = l >> 4;

    // ---- stage A: conv = ag@Wc (32x128); wave w: nt in {2w,2w+1} ----
    {
        f32x4 acc[2][2];
#pragma unroll
        for (int mi = 0; mi < 2; ++mi)
#pragma unroll
            for (int ni = 0; ni < 2; ++ni) acc[mi][ni] = (f32x4){0.f, 0.f, 0.f, 0.f};
#pragma unroll
        for (int kt = 0; kt < 4; ++kt) {
            int ka = kt * 32 + lg * 8;
            s16x8 a0h = *(const s16x8*)(ag_hi + lr * 136 + ka);
            s16x8 a0l = *(const s16x8*)(ag_lo + lr * 136 + ka);
            s16x8 a1h = *(const s16x8*)(ag_hi + (16 + lr) * 136 + ka);
            s16x8 a1l = *(const s16x8*)(ag_lo + (16 + lr) * 136 + ka);
#pragma unroll
            for (int ni = 0; ni < 2; ++ni) {
                int nt = 2 * w + ni;
                const u16* bp = wp + (kt * 8 + nt) * 1024 + l * 8;
                s16x8 bh = *(const s16x8*)(bp);
                s16x8 bl = *(const s16x8*)(bp + 512);
                acc[0][ni] = __builtin_amdgcn_mfma_f32_16x16x32_bf16(a0h, bl, acc[0][ni], 0, 0, 0);
                acc[0][ni] = __builtin_amdgcn_mfma_f32_16x16x32_bf16(a0l, bh, acc[0][ni], 0, 0, 0);
                acc[0][ni] = __builtin_amdgcn_mfma_f32_16x16x32_bf16(a0h, bh, acc[0][ni], 0, 0, 0);
                acc[1][ni] = __builtin_amdgcn_mfma_f32_16x16x32_bf16(a1h, bl, acc[1][ni], 0, 0, 0);
                acc[1][ni] = __builtin_amdgcn_mfma_f32_16x16x32_bf16(a1l, bh, acc[1][ni], 0, 0, 0);
                acc[1][ni] = __builtin_amdgcn_mfma_f32_16x16x32_bf16(a1h, bh, acc[1][ni], 0, 0, 0);
            }
        }
        __syncthreads();   // ag reads done before rs writes / later hs overlay
#pragma unroll
        for (int ni = 0; ni < 2; ++ni) {
            int col = (2 * w + ni) * 16 + lr;
            float bias = bc[col];
#pragma unroll
            for (int mi = 0; mi < 2; ++mi)
#pragma unroll
                for (int r = 0; r < 4; ++r) {
                    int row = mi * 16 + lg * 4 + r;
                    float v = acc[mi][ni][r] + bias;
                    v = fmaxf(v, 0.f) + x0[(size_t)(row0 + row) * Fn + col];
                    u16 h = f2bf(v);
                    rs_hi[row * 136 + col] = h;
                    rs_lo[row * 136 + col] = f2bf(v - bf2f(h));
                }
        }
    }
    __syncthreads();

    // ---- stage B: hs = leaky(rs@W1 + b1) (32x256); nt in {4w..4w+3} ----
    {
        const u16* w1p = wp + 32768;
        f32x4 acc[2][4];
#pragma unroll
        for (int mi = 0; mi < 2; ++mi)
#pragma unroll
            for (int ni = 0; ni < 4; ++ni) acc[mi][ni] = (f32x4){0.f, 0.f, 0.f, 0.f};
#pragma unroll
        for (int kt = 0; kt < 4; ++kt) {
            int ka = kt * 32 + lg * 8;
            s16x8 a0h = *(const s16x8*)(rs_hi + lr * 136 + ka);
            s16x8 a0l = *(const s16x8*)(rs_lo + lr * 136 + ka);
            s16x8 a1h = *(const s16x8*)(rs_hi + (16 + lr) * 136 + ka);
            s16x8 a1l = *(const s16x8*)(rs_lo + (16 + lr) * 136 + ka);
#pragma unroll
            for (int ni = 0; ni < 4; ++ni) {
                int nt = 4 * w + ni;
                const u16* bp = w1p + (kt * 16 + nt) * 1024 + l * 8;
                s16x8 bh = *(const s16x8*)(bp);
                s16x8 bl = *(const s16x8*)(bp + 512);
                acc[0][ni] = __builtin_amdgcn_mfma_f32_16x16x32_bf16(a0h, bl, acc[0][ni], 0, 0, 0);
                acc[0][ni] = __builtin_amdgcn_mfma_f32_16x16x32_bf16(a0l, bh, acc[0][ni], 0, 0, 0);
                acc[0][ni] = __builtin_amdgcn_mfma_f32_16x16x32_bf16(a0h, bh, acc[0][ni], 0, 0, 0);
                acc[1][ni] = __builtin_amdgcn_mfma_f32_16x16x32_bf16(a1h, bl, acc[1][ni], 0, 0, 0);
                acc[1][ni] = __builtin_amdgcn_mfma_f32_16x16x32_bf16(a1l, bh, acc[1][ni], 0, 0, 0);
                acc[1][ni] = __builtin_amdgcn_mfma_f32_16x16x32_bf16(a1h, bh, acc[1][ni], 0, 0, 0);
            }
        }
#pragma unroll
        for (int ni = 0; ni < 4; ++ni) {
            int col = (4 * w + ni) * 16 + lr;
            float bias = b1[col];
#pragma unroll
            for (int mi = 0; mi < 2; ++mi)
#pragma unroll
                for (int r = 0; r < 4; ++r) {
                    int row = mi * 16 + lg * 4 + r;
                    float v = acc[mi][ni][r] + bias;
                    v = v > 0.f ? v : 0.01f * v;
                    u16 h = f2bf(v);
                    hs_hi[row * 264 + col] = h;
                    hs_lo[row * 264 + col] = f2bf(v - bf2f(h));
                }
        }
    }
    __syncthreads();

    // ---- stage C: out = leaky(hs@W2 + b2) (32x256), K=256 ----
    {
        const u16* w2p = wp + 98304;
        f32x4 acc[2][4];
#pragma unroll
        for (int mi = 0; mi < 2; ++mi)
#pragma unroll
            for (int ni = 0; ni < 4; ++ni) acc[mi][ni] = (f32x4){0.f, 0.f, 0.f, 0.f};
#pragma unroll
        for (int kt = 0; kt < 8; ++kt) {
            int ka = kt * 32 + lg * 8;
            s16x8 a0h = *(const s16x8*)(hs_hi + lr * 264 + ka);
            s16x8 a0l = *(const s16x8*)(hs_lo + lr * 264 + ka);
            s16x8 a1h = *(const s16x8*)(hs_hi + (16 + lr) * 264 + ka);
            s16x8 a1l = *(const s16x8*)(hs_lo + (16 + lr) * 264 + ka);
#pragma unroll
            for (int ni = 0; ni < 4; ++ni) {
                int nt = 4 * w + ni;
                const u16* bp = w2p + (kt * 16 + nt) * 1024 + l * 8;
                s16x8 bh = *(const s16x8*)(bp);
                s16x8 bl = *(const s16x8*)(bp + 512);
                acc[0][ni] = __builtin_amdgcn_mfma_f32_16x16x32_bf16(a0h, bl, acc[0][ni], 0, 0, 0);
                acc[0][ni] = __builtin_amdgcn_mfma_f32_16x16x32_bf16(a0l, bh, acc[0][ni], 0, 0, 0);
                acc[0][ni] = __builtin_amdgcn_mfma_f32_16x16x32_bf16(a0h, bh, acc[0][ni], 0, 0, 0);
                acc[1][ni] = __builtin_amdgcn_mfma_f32_16x16x32_bf16(a1h, bl, acc[1][ni], 0, 0, 0);
                acc[1][ni] = __builtin_amdgcn_mfma_f32_16x16x32_bf16(a1l, bh, acc[1][ni], 0, 0, 0);
                acc[1][ni] = __builtin_amdgcn_mfma_f32_16x16x32_bf16(a1h, bh, acc[1][ni], 0, 0, 0);
            }
        }
#pragma unroll
        for (int ni = 0; ni < 4; ++ni) {
            int col = (4 * w + ni) * 16 + lr;
            float bias = b2[col];
#pragma unroll
            for (int mi = 0; mi < 2; ++mi)
#pragma unroll
                for (int r = 0; r < 4; ++r) {
                    int row = mi * 16 + lg * 4 + r;
                    float v = acc[mi][ni][r] + bias;
                    v = v > 0.f ? v : 0.01f * v;
                    out[((size_t)(row0 + row) << 8) + col] = v;
                }
        }
    }
}

// GEMM kernel: copy packed AGG planes from out, then chain.
__global__ __launch_bounds__(256, 3) void k_fmfma(
        const float* __restrict__ x0, const u16* __restrict__ wp,
        const float* __restrict__ bc, const float* __restrict__ b1,
        const float* __restrict__ b2, float* out) {
    __shared__ __align__(16) u16 sm[25600];
    u16* rs_hi = sm;
    u16* rs_lo = sm + 4352;
    u16* ag_hi = sm + 8704;
    u16* ag_lo = sm + 13056;
    u16* hs_hi = sm + 8704;
    u16* hs_lo = sm + 17152;

    int row0 = blockIdx.x * TM;
    int t = threadIdx.x;
    int w = t >> 6;
    int l = t & 63;

#pragma unroll
    for (int it = 0; it < 4; ++it) {
        int idx = it * 256 + t;
        int r = idx >> 5, q = idx & 31;
        uint4 v = *(const uint4*)((const char*)out +
                                  ((size_t)(row0 + r) << 10) + (q << 4));
        u16* dst = (q < 16) ? (ag_hi + r * 136 + (q << 3))
                            : (ag_lo + r * 136 + ((q - 16) << 3));
        *(uint4*)dst = v;
    }
    __syncthreads();

    gemm_chain(x0, wp, bc, b1, b2, out,
               rs_hi, rs_lo, ag_hi, ag_lo, hs_hi, hs_lo, row0, w, l);
}

// ---------------------------------------------------------------------------
// Tier-2 standalone gather (f16 table lives inside out rows [512,768)).
// ---------------------------------------------------------------------------
__device__ __forceinline__ void g_edge(const char* __restrict__ outc, int s,
                                       float w, int lane, float& ax, float& ay) {
    __half2 h = *(const __half2*)(outc + ((size_t)s << 10) + 512 + 4 * lane);
    float2 v = __half22float2(h);
    ax = fmaf(w, v.x, ax);
    ay = fmaf(w, v.y, ay);
}

__global__ __launch_bounds__(256) void k_gather(
        const float* __restrict__ dinv,
        const int* __restrict__ row_start, const int* __restrict__ row_end,
        const int* __restrict__ elist, const float* __restrict__ wl,
        float* __restrict__ out) {
    int sb = (blockIdx.x & 7) * 2500 + (blockIdx.x >> 3);   // XCD chunking
    int wid = ((sb * 256 + (int)threadIdx.x) >> 6);
    int lane = threadIdx.x & 63;
    if (wid >= NROW) return;
    const char* outc = (const char*)out;
    int rs = row_start[wid], re = row_end[wid];
    float ax = 0.f, ay = 0.f;
    int j = rs;
    if (wl) {
        while (j < re && (j & 3)) { g_edge(outc, elist[j], wl[j], lane, ax, ay); ++j; }
        for (; j + 8 <= re; j += 8) {
            int4   ea = *(const int4*)(elist + j);
            int4   eb = *(const int4*)(elist + j + 4);
            float4 wa = *(const float4*)(wl + j);
            float4 wb = *(const float4*)(wl + j + 4);
            g_edge(outc, ea.x, wa.x, lane, ax, ay);
            g_edge(outc, ea.y, wa.y, lane, ax, ay);
            g_edge(outc, ea.z, wa.z, lane, ax, ay);
            g_edge(outc, ea.w, wa.w, lane, ax, ay);
            g_edge(outc, eb.x, wb.x, lane, ax, ay);
            g_edge(outc, eb.y, wb.y, lane, ax, ay);
            g_edge(outc, eb.z, wb.z, lane, ax, ay);
            g_edge(outc, eb.w, wb.w, lane, ax, ay);
        }
        if (j + 4 <= re) {
            int4   ea = *(const int4*)(elist + j);
            float4 wa = *(const float4*)(wl + j);
            g_edge(outc, ea.x, wa.x, lane, ax, ay);
            g_edge(outc, ea.y, wa.y, lane, ax, ay);
            g_edge(outc, ea.z, wa.z, lane, ax, ay);
            g_edge(outc, ea.w, wa.w, lane, ax, ay);
            j += 4;
        }
        for (; j < re; ++j) g_edge(outc, elist[j], wl[j], lane, ax, ay);
    } else {
        for (; j + 4 <= re; j += 4) {
            int s0 = elist[j], s1 = elist[j + 1], s2 = elist[j + 2], s3 = elist[j + 3];
            float w0 = dinv[s0], w1 = dinv[s1], w2 = dinv[s2], w3 = dinv[s3];
            g_edge(outc, s0, w0, lane, ax, ay);
            g_edge(outc, s1, w1, lane, ax, ay);
            g_edge(outc, s2, w2, lane, ax, ay);
            g_edge(outc, s3, w3, lane, ax, ay);
        }
        for (; j < re; ++j) {
            int s = elist[j];
            g_edge(outc, s, dinv[s], lane, ax, ay);
        }
    }
    float wd = dinv[wid];
    g_edge(outc, wid, wd, lane, ax, ay);
    float sx = wd * ax, sy = wd * ay;
    u16 h0 = f2bf(sx), h1 = f2bf(sy);
    u16 l0 = f2bf(sx - bf2f(h0)), l1 = f2bf(sy - bf2f(h1));
    unsigned* orow = (unsigned*)(out + ((size_t)wid << 8));
    orow[lane]      = (unsigned)h0 | ((unsigned)h1 << 16);
    orow[64 + lane] = (unsigned)l0 | ((unsigned)l1 << 16);
}

// ---------------------------------------------------------------------------
// Full fallback (tiny workspace): float degree + atomic scatter + f32 fused.
// ---------------------------------------------------------------------------
__global__ void k_canary(float* out) {
    if (threadIdx.x == 0 && blockIdx.x == 0) out[4] = 1000.0f;
}
__global__ void k_deg_init(float* __restrict__ deg) {
    int i = blockIdx.x * blockDim.x + threadIdx.x;
    if (i < NROW) deg[i] = 1.0f;
}
__global__ void k_deg_count(const int* __restrict__ e, float* __restrict__ deg) {
    bool i64 = edge_is_i64(e);
    int i = blockIdx.x * blockDim.x + threadIdx.x;
    if (i >= NEDGE) return;
    int b = i / En, k = i - b * En;
    int dst = eidx(e, (long long)(b * 2 + 1) * En + k, i64);
    if ((unsigned)dst < Nn) atomicAdd(&deg[b * Nn + dst], 1.0f);
}
__global__ void k_dinv(float* __restrict__ deg) {
    int i = blockIdx.x * blockDim.x + threadIdx.x;
    if (i < NROW) deg[i] = rsqrtf(deg[i]);
}
__global__ void k_agg_init(const float* __restrict__ x0,
                           const float* __restrict__ dinv,
                           float* __restrict__ out) {
    int i = blockIdx.x * blockDim.x + threadIdx.x;
    if (i >= NROW * Fn) return;
    int r = i >> 7;
    int c = i & 127;
    float dv = dinv[r];
    out[((size_t)r << 8) + c] = dv * dv * x0[i];
}
__global__ void k_scatter(const int* __restrict__ e,
                          const float* __restrict__ dinv,
                          const float* __restrict__ x0,
                          float* __restrict__ out) {
    bool i64 = edge_is_i64(e);
    long long gid = (long long)blockIdx.x * blockDim.x + threadIdx.x;
    int eid = (int)(gid >> 6);
    int lane = (int)(gid & 63);
    if (eid >= NEDGE) return;
    int b = eid / En, k = eid - b * En;
    int src = eidx(e, (long long)(b * 2) * En + k, i64);
    int dst = eidx(e, (long long)(b * 2 + 1) * En + k, i64);
    if ((unsigned)src >= Nn || (unsigned)dst >= Nn) return;
    float nrm = dinv[b * Nn + src] * dinv[b * Nn + dst];
    const float2 vf =
        *(const float2*)(x0 + ((size_t)(b * Nn + src) << 7) + 2 * lane);
    float* p = out + ((size_t)(b * Nn + dst) << 8) + 2 * lane;
    atomicAdd(p, nrm * vf.x);
    atomicAdd(p + 1, nrm * vf.y);
}

__global__ __launch_bounds__(256, 3) void k_fused(
        const float* __restrict__ x0,
        const float* __restrict__ Wc, const float* __restrict__ bc,
        const float* __restrict__ W1, const float* __restrict__ b1,
        const float* __restrict__ W2, const float* __restrict__ b2,
        float* out) {
    __shared__ float smem[12352];
    float (*rs)[Fn + 1] = (float (*)[Fn + 1])smem;
    float (*ag)[Fn + 1] = (float (*)[Fn + 1])(smem + 4128);
    float (*hs)[Hn + 1] = (float (*)[Hn + 1])(smem + 4128);

    int row0 = blockIdx.x * TM;
    int t = threadIdx.x;
    int tx = t & 31;
    int ty = t >> 5;
    int ra = ty * 4;

    for (int i = t; i < TM * Fn; i += 256) {
        int r = i >> 7, c = i & 127;
        ag[r][c] = out[((size_t)(row0 + r) << 8) + c];
    }
    __syncthreads();
    {
        float acc[4][4] = {};
#pragma unroll 4
        for (int k = 0; k < Fn; ++k) {
            float a0 = ag[ra + 0][k], a1 = ag[ra + 1][k],
                  a2 = ag[ra + 2][k], a3 = ag[ra + 3][k];
            const float4 b = *(const float4*)(Wc + k * Fn + tx * 4);
            acc[0][0] = fmaf(a0, b.x, acc[0][0]); acc[0][1] = fmaf(a0, b.y, acc[0][1]);
            acc[0][2] = fmaf(a0, b.z, acc[0][2]); acc[0][3] = fmaf(a0, b.w, acc[0][3]);
            acc[1][0] = fmaf(a1, b.x, acc[1][0]); acc[1][1] = fmaf(a1, b.y, acc[1][1]);
            acc[1][2] = fmaf(a1, b.z, acc[1][2]); acc[1][3] = fmaf(a1, b.w, acc[1][3]);
            acc[2][0] = fmaf(a2, b.x, acc[2][0]); acc[2][1] = fmaf(a2, b.y, acc[2][1]);
            acc[2][2] = fmaf(a2, b.z, acc[2][2]); acc[2][3] = fmaf(a2, b.w, acc[2][3]);
            acc[3][0] = fmaf(a3, b.x, acc[3][0]); acc[3][1] = fmaf(a3, b.y, acc[3][1]);
            acc[3][2] = fmaf(a3, b.z, acc[3][2]); acc[3][3] = fmaf(a3, b.w, acc[3][3]);
        }
        const float4 bcv = *(const float4*)(bc + tx * 4);
        __syncthreads();
#pragma unroll
        for (int i = 0; i < 4; ++i) {
            const float4 xv =
                *(const float4*)(x0 + (size_t)(row0 + ra + i) * Fn + tx * 4);
            rs[ra + i][tx * 4 + 0] = fmaxf(acc[i][0] + bcv.x, 0.f) + xv.x;
            rs[ra + i][tx * 4 + 1] = fmaxf(acc[i][1] + bcv.y, 0.f) + xv.y;
            rs[ra + i][tx * 4 + 2] = fmaxf(acc[i][2] + bcv.z, 0.f) + xv.z;
            rs[ra + i][tx * 4 + 3] = fmaxf(acc[i][3] + bcv.w, 0.f) + xv.w;
        }
    }
    __syncthreads();
    {
        float acc[4][8] = {};
#pragma unroll 2
        for (int k = 0; k < Fn; ++k) {
            float a0 = rs[ra + 0][k], a1 = rs[ra + 1][k],
                  a2 = rs[ra + 2][k], a3 = rs[ra + 3][k];
            const float4 p0 = *(const float4*)(W1 + k * Hn + tx * 8);
            const float4 p1 = *(const float4*)(W1 + k * Hn + tx * 8 + 4);
#pragma unroll
            for (int i = 0; i < 4; ++i) {
                float a = (i == 0) ? a0 : (i == 1) ? a1 : (i == 2) ? a2 : a3;
                acc[i][0] = fmaf(a, p0.x, acc[i][0]); acc[i][1] = fmaf(a, p0.y, acc[i][1]);
                acc[i][2] = fmaf(a, p0.z, acc[i][2]); acc[i][3] = fmaf(a, p0.w, acc[i][3]);
                acc[i][4] = fmaf(a, p1.x, acc[i][4]); acc[i][5] = fmaf(a, p1.y, acc[i][5]);
                acc[i][6] = fmaf(a, p1.z, acc[i][6]); acc[i][7] = fmaf(a, p1.w, acc[i][7]);
            }
        }
        const float4 b1a = *(const float4*)(b1 + tx * 8);
        const float4 b1b = *(const float4*)(b1 + tx * 8 + 4);
        float bias[8] = {b1a.x, b1a.y, b1a.z, b1a.w, b1b.x, b1b.y, b1b.z, b1b.w};
#pragma unroll
        for (int i = 0; i < 4; ++i)
#pragma unroll
            for (int j = 0; j < 8; ++j) {
                float h = acc[i][j] + bias[j];
                hs[ra + i][tx * 8 + j] = h > 0.f ? h : 0.01f * h;
            }
    }
    __syncthreads();
    {
        float acc[4][8] = {};
#pragma unroll 2
        for (int k = 0; k < Hn; ++k) {
            float a0 = hs[ra + 0][k], a1 = hs[ra + 1][k],
                  a2 = hs[ra + 2][k], a3 = hs[ra + 3][k];
            const float4 p0 = *(const float4*)(W2 + k * Hn + tx * 8);
            const float4 p1 = *(const float4*)(W2 + k * Hn + tx * 8 + 4);
#pragma unroll
            for (int i = 0; i < 4; ++i) {
                float a = (i == 0) ? a0 : (i == 1) ? a1 : (i == 2) ? a2 : a3;
                acc[i][0] = fmaf(a, p0.x, acc[i][0]); acc[i][1] = fmaf(a, p0.y, acc[i][1]);
                acc[i][2] = fmaf(a, p0.z, acc[i][2]); acc[i][3] = fmaf(a, p0.w, acc[i][3]);
                acc[i][4] = fmaf(a, p1.x, acc[i][4]); acc[i][5] = fmaf(a, p1.y, acc[i][5]);
                acc[i][6] = fmaf(a, p1.z, acc[i][6]); acc[i][7] = fmaf(a, p1.w, acc[i][7]);
            }
        }
        const float4 b2a = *(const float4*)(b2 + tx * 8);
        const float4 b2b = *(const float4*)(b2 + tx * 8 + 4);
        float bias[8] = {b2a.x, b2a.y, b2a.z, b2a.w, b2b.x, b2b.y, b2b.z, b2b.w};
#pragma unroll
        for (int i = 0; i < 4; ++i) {
            float o[8];
#pragma unroll
            for (int j = 0; j < 8; ++j) {
                float v = acc[i][j] + bias[j];
                o[j] = v > 0.f ? v : 0.01f * v;
            }
            float* dst = out + ((size_t)(row0 + ra + i) << 8) + tx * 8;
            *(float4*)(dst)     = make_float4(o[0], o[1], o[2], o[3]);
            *(float4*)(dst + 4) = make_float4(o[4], o[5], o[6], o[7]);
        }
    }
}

// ---------------------------------------------------------------------------
extern "C" void kernel_launch(void* const* d_in, const int* in_sizes, int n_in,
                              void* d_out, int out_size, void* d_ws, size_t ws_size,
                              hipStream_t stream) {
    const float* x0 = (const float*)d_in[0];
    const int*   ed = (const int*)d_in[1];
    const float* Wc = (const float*)d_in[2];
    const float* bc = (const float*)d_in[3];
    const float* W1 = (const float*)d_in[4];
    const float* b1 = (const float*)d_in[5];
    const float* W2 = (const float*)d_in[6];
    const float* b2 = (const float*)d_in[7];

    float* out = (float*)d_out;
    int*   wsi = (int*)d_ws;
    float* wsf = (float*)d_ws;

    bool t3 = ws_size >= WS3_BYTES;
    bool t2 = ws_size >= WS2_BYTES;
    bool t1 = ws_size >= WS1_BYTES;

    if (t1 || t2 || t3) {
        int*   degi      = wsi;                 // -> dinv (f32) after scan3
        float* dinv      = wsf;
        int*   row_start = wsi + OFF_RS;
        int*   cursor    = wsi + OFF_CUR;
        int*   bsum      = wsi + OFF_BS;
        int*   boff      = wsi + OFF_BO;
        int*   elist     = wsi + OFF_EL;
        float* wl        = (t2 || t3) ? (wsf + OFF_WL) : nullptr;
        u16*   wp        = (u16*)(wsi + ((t2 || t3) ? WS2_INTS : WS1_INTS));
        __half* x0h      = (__half*)((char*)d_ws + WS2_BYTES);

        if (t3) {
            k_init3<<<10000, 256, 0, stream>>>(degi, x0h, x0, out);
        } else {
            k_init<<<313, 256, 0, stream>>>(degi, out);
            k_xh<<<10000, 256, 0, stream>>>(x0, out);
        }
        k_deg_count_i<<<(NEDGE + 255) / 256, 256, 0, stream>>>(ed, degi);
        k_scan1<<<313, 256, 0, stream>>>(degi, row_start, bsum);
        k_scan2<<<1, 512, 0, stream>>>(bsum, boff, row_start);
        k_scan3<<<313, 256, 0, stream>>>(degi, dinv, row_start, boff, cursor);
        k_bin<<<(NEDGE + 255) / 256, 256, 0, stream>>>(ed, dinv, cursor, elist, wl);
        k_wpack<<<448, 256, 0, stream>>>(Wc, W1, W2, wp);
        if (t3) {
            k_gather3<<<NROW / 4, 256, 0, stream>>>(
                x0h, dinv, row_start, cursor, elist, wl, out);
        } else {
            k_gather<<<NROW / 4, 256, 0, stream>>>(
                dinv, row_start, cursor, elist, wl, out);
        }
        k_fmfma<<<NROW / TM, 256, 0, stream>>>(x0, wp, bc, b1, b2, out);
    } else {
        float* deg = wsf;
        k_canary<<<1, 64, 0, stream>>>(out);
        k_deg_init<<<(NROW + 255) / 256, 256, 0, stream>>>(deg);
        k_deg_count<<<(NEDGE + 255) / 256, 256, 0, stream>>>(ed, deg);
        k_dinv<<<(NROW + 255) / 256, 256, 0, stream>>>(deg);
        k_agg_init<<<(NROW * Fn + 255) / 256, 256, 0, stream>>>(x0, deg, out);
        long long sthreads = (long long)NEDGE * 64;
        k_scatter<<<(int)((sthreads + 255) / 256), 256, 0, stream>>>(ed, deg, x0, out);
        k_fused<<<NROW / TM, 256, 0, stream>>>(x0, Wc, bc, W1, b1, W2, b2, out);
    }
}

// Round 6
// 345.851 us; speedup vs baseline: 1.2033x; 1.1122x over previous
//
#include <hip/hip_runtime.h>
#include <hip/hip_bf16.h>
#include <hip/hip_fp16.h>

// Problem constants: B=8, N=10000, E=160000, F=128, H=256
#define Bn 8
#define Nn 10000
#define En 160000
#define Fn 128
#define Hn 256
#define NROW (Bn * Nn)     // 80,000
#define NEDGE (Bn * En)    // 1,280,000
#define TM 32              // rows per block in fused epilogue

// Workspace layout (ints):
//   [0,80000)            deg (int) -> dinv (f32) after k_scan3
//   [80000,160001)       row_start
//   [160004,240004)      cursor
//   [240004,240317)      bsum (313)
//   [240320,240832)      boff (512)
//   [240832,2800832)     ep: int2 {src, bits(dinv[src])} per edge, CSR order
//   then 262,144 B packed weights (u16): Wc split-bf16 [0,32768),
//        W1 f16 [32768,65536), W2 f16 [65536,131072)
//   then 20,480,000 B x0 as f16 [NROW][128].
// out row layout (1024 B): [0,256)=AGG hi bf16, [256,512)=AGG lo bf16
//   (gather writes; k_fmfma stage C overwrites all 1024 B).
// R6: stages B/C single-f16 MFMA (144 vs 336 MFMA/wave), LDS 51.2->26.1 KB
//   (6 blk/CU); edge kernels 2-edge vectorized; (src,w) fused 8B records.
#define OFF_RS   80000
#define OFF_CUR  160004
#define OFF_BS   240004
#define OFF_BO   240320
#define OFF_EP   240832
#define WSI_END  2800832
#define WP_U16   131072
#define WP_BYTES ((size_t)WP_U16 * 2)                 // 262,144
#define X0H_BYTES ((size_t)NROW * Fn * 2)             // 20,480,000
#define X0H_OFF  ((size_t)WSI_END * 4 + WP_BYTES)     // 11,465,472
#define WS_NEED  (X0H_OFF + X0H_BYTES)                // 31,945,472

typedef unsigned short u16;
typedef __attribute__((ext_vector_type(8))) short s16x8;
typedef __attribute__((ext_vector_type(8))) _Float16 f16x8;
typedef __attribute__((ext_vector_type(4))) float f32x4;

__device__ __forceinline__ u16 f2bf(float x) {           // RNE f32->bf16
    unsigned u = __float_as_uint(x);
    u += 0x7FFF + ((u >> 16) & 1);
    return (u16)(u >> 16);
}
__device__ __forceinline__ float bf2f(u16 h) {
    return __uint_as_float((unsigned)h << 16);
}
__device__ __forceinline__ u16 f2h(float x) {            // RNE f32->f16 bits
    _Float16 h = (_Float16)x;
    return *(u16*)&h;
}

__device__ __forceinline__ bool edge_is_i64(const int* e) {
    return e[1] == 0 && e[3] == 0;
}
__device__ __forceinline__ int eidx(const int* e, long long i, bool i64) {
    return i64 ? e[2 * i] : e[i];
}

// ---------------------------------------------------------------------------
// k_prep: deg=1 + canary + x0->f16 table (blocks 0..9999) and weight pack
// (blocks 10000..10447).
// Weight pack k-map: k = kt*32 + (l>>4)*8 + j (same map as A-frags).
// ---------------------------------------------------------------------------
__global__ void k_prep(int* __restrict__ deg, __half* __restrict__ x0h,
                       const float* __restrict__ x0, float* __restrict__ out,
                       const float* __restrict__ Wc, const float* __restrict__ W1,
                       const float* __restrict__ W2, u16* __restrict__ wp) {
    if (blockIdx.x < 10000) {
        int i = blockIdx.x * 256 + threadIdx.x;     // < NROW*32
        if (i < NROW) deg[i] = 1;
        if (i == 0) out[4] = 1000.0f;               // erased by k_gather3
        int r = i >> 5, g = i & 31;
        float4 v = *(const float4*)(x0 + ((size_t)r << 7) + (g << 2));
        __half2 a = __floats2half2_rn(v.x, v.y);
        __half2 b = __floats2half2_rn(v.z, v.w);
        uint2 u;
        u.x = *(unsigned*)&a;
        u.y = *(unsigned*)&b;
        *(uint2*)((char*)x0h + ((size_t)r << 8) + (g << 3)) = u;
    } else {
        int i = (blockIdx.x - 10000) * 256 + threadIdx.x;   // < 114688
        if (i < 16384) {                 // Wc: split-bf16, NT=8
            int j = i & 7, l = (i >> 3) & 63;
            int nt = (i >> 9) & 7, kt = i >> 12;
            int k = kt * 32 + (l >> 4) * 8 + j;
            int n = nt * 16 + (l & 15);
            float v = Wc[(size_t)k * Fn + n];
            u16 hi = f2bf(v);
            u16 lo = f2bf(v - bf2f(hi));
            int o = (kt * 8 + nt) * 1024 + l * 8 + j;
            wp[o] = hi;
            wp[o + 512] = lo;
        } else if (i < 49152) {          // W1: f16 single, NT=16, kt<4
            int idx = i - 16384;
            int j = idx & 7, l = (idx >> 3) & 63;
            int nt = (idx >> 9) & 15, kt = idx >> 13;
            int k = kt * 32 + (l >> 4) * 8 + j;
            int n = nt * 16 + (l & 15);
            wp[32768 + (kt * 16 + nt) * 512 + l * 8 + j] =
                f2h(W1[(size_t)k * Hn + n]);
        } else if (i < 114688) {         // W2: f16 single, NT=16, kt<8
            int idx = i - 49152;
            int j = idx & 7, l = (idx >> 3) & 63;
            int nt = (idx >> 9) & 15, kt = idx >> 13;
            int k = kt * 32 + (l >> 4) * 8 + j;
            int n = nt * 16 + (l & 15);
            wp[65536 + (kt * 16 + nt) * 512 + l * 8 + j] =
                f2h(W2[(size_t)k * Hn + n]);
        }
    }
}

// ---------------------------------------------------------------------------
// Degree count, 2 edges/thread (int4 read of the i64 dst stream).
// ---------------------------------------------------------------------------
__global__ void k_deg2(const int* __restrict__ e, int* __restrict__ deg) {
    bool i64 = edge_is_i64(e);
    int p = blockIdx.x * blockDim.x + threadIdx.x;   // pair index
    if (p >= NEDGE / 2) return;
    int b = p / (En / 2);
    int kk = (p - b * (En / 2)) * 2;
    int d0, d1;
    if (i64) {
        int4 v = *(const int4*)(e + ((long long)(b * 2 + 1) * En + kk) * 2);
        d0 = v.x; d1 = v.z;
    } else {
        int2 v = *(const int2*)(e + (long long)(b * 2 + 1) * En + kk);
        d0 = v.x; d1 = v.y;
    }
    if ((unsigned)d0 < Nn) atomicAdd(&deg[b * Nn + d0], 1);
    if ((unsigned)d1 < Nn) atomicAdd(&deg[b * Nn + d1], 1);
}

// ---------------------------------------------------------------------------
// Exclusive scan of in-degree over 80,000 rows, 3 kernels.
// ---------------------------------------------------------------------------
__global__ void k_scan1(const int* __restrict__ deg,
                        int* __restrict__ row_start, int* __restrict__ bsum) {
    __shared__ int s[256];
    int i = blockIdx.x * 256 + threadIdx.x;
    int v = (i < NROW) ? (deg[i] - 1) : 0;
    s[threadIdx.x] = v;
    __syncthreads();
    for (int off = 1; off < 256; off <<= 1) {
        int t = (threadIdx.x >= off) ? s[threadIdx.x - off] : 0;
        __syncthreads();
        s[threadIdx.x] += t;
        __syncthreads();
    }
    if (i < NROW) row_start[i] = s[threadIdx.x] - v;
    if (threadIdx.x == 255) bsum[blockIdx.x] = s[255];
}

__global__ void k_scan2(const int* __restrict__ bsum, int* __restrict__ boff,
                        int* __restrict__ row_start) {
    __shared__ int s[512];
    int t = threadIdx.x;
    int v = (t < 313) ? bsum[t] : 0;
    s[t] = v;
    __syncthreads();
    for (int off = 1; off < 512; off <<= 1) {
        int u = (t >= off) ? s[t - off] : 0;
        __syncthreads();
        s[t] += u;
        __syncthreads();
    }
    boff[t] = s[t] - v;
    if (t == 511) row_start[NROW] = s[511];
}

__global__ void k_scan3(int* __restrict__ degi, float* __restrict__ dinvf,
                        int* __restrict__ row_start,
                        const int* __restrict__ boff, int* __restrict__ cursor) {
    int i = blockIdx.x * blockDim.x + threadIdx.x;
    if (i >= NROW) return;
    int v = row_start[i] + boff[i >> 8];
    row_start[i] = v;
    cursor[i] = v;
    float d = (float)degi[i];
    dinvf[i] = rsqrtf(d);
}

// ---------------------------------------------------------------------------
// Counting-sort, 2 edges/thread; 8B fused (src, dinv-bits) records.
// ---------------------------------------------------------------------------
__global__ void k_bin2(const int* __restrict__ e, const float* __restrict__ dinv,
                       int* __restrict__ cursor, int2* __restrict__ ep) {
    bool i64 = edge_is_i64(e);
    int p = blockIdx.x * blockDim.x + threadIdx.x;
    if (p >= NEDGE / 2) return;
    int b = p / (En / 2);
    int kk = (p - b * (En / 2)) * 2;
    int s0, s1, d0, d1;
    if (i64) {
        int4 sv = *(const int4*)(e + ((long long)(b * 2) * En + kk) * 2);
        int4 dv = *(const int4*)(e + ((long long)(b * 2 + 1) * En + kk) * 2);
        s0 = sv.x; s1 = sv.z; d0 = dv.x; d1 = dv.z;
    } else {
        int2 sv = *(const int2*)(e + (long long)(b * 2) * En + kk);
        int2 dv = *(const int2*)(e + (long long)(b * 2 + 1) * En + kk);
        s0 = sv.x; s1 = sv.y; d0 = dv.x; d1 = dv.y;
    }
    if ((unsigned)s0 < Nn && (unsigned)d0 < Nn) {
        int g = b * Nn + s0;
        int pos = atomicAdd(&cursor[b * Nn + d0], 1);
        ep[pos] = make_int2(g, __float_as_int(dinv[g]));
    }
    if ((unsigned)s1 < Nn && (unsigned)d1 < Nn) {
        int g = b * Nn + s1;
        int pos = atomicAdd(&cursor[b * Nn + d1], 1);
        ep[pos] = make_int2(g, __float_as_int(dinv[g]));
    }
}

// ---------------------------------------------------------------------------
// Gather: one wave per row, 2 cols/lane, zero LDS (full occupancy hides L2
// latency — R4 lesson). Reads f16 x0h (2.56 MB/graph, XCD-L2-resident via
// chunking) + 8B edge records; writes AGG bf16 hi/lo planes to out[0,512).
// ---------------------------------------------------------------------------
__device__ __forceinline__ void g_edge_h(const __half* __restrict__ x0h, int s,
                                         float w, int lane, float& ax, float& ay) {
    __half2 h = *(const __half2*)(x0h + ((size_t)s << 7) + 2 * lane);
    float2 v = __half22float2(h);
    ax = fmaf(w, v.x, ax);
    ay = fmaf(w, v.y, ay);
}
__device__ __forceinline__ void g_pair(const __half* __restrict__ x0h,
                                       int4 pq, int lane, float& ax, float& ay) {
    g_edge_h(x0h, pq.x, __int_as_float(pq.y), lane, ax, ay);
    g_edge_h(x0h, pq.z, __int_as_float(pq.w), lane, ax, ay);
}

__global__ __launch_bounds__(256) void k_gather3(
        const __half* __restrict__ x0h, const float* __restrict__ dinv,
        const int* __restrict__ row_start, const int* __restrict__ row_end,
        const int2* __restrict__ ep, float* __restrict__ out) {
    // XCD chunking: 20,000 blocks = 8 * 2500; chunk per XCD = one graph.
    int sb = (blockIdx.x & 7) * 2500 + (blockIdx.x >> 3);
    int wid = ((sb * 256 + (int)threadIdx.x) >> 6);
    int lane = threadIdx.x & 63;
    if (wid >= NROW) return;
    int rs = row_start[wid], re = row_end[wid];
    float wd = dinv[wid];
    float ax = 0.f, ay = 0.f;
    int j = rs;
    if (j < re && (j & 1)) {            // peel to int4 alignment
        int2 q = ep[j];
        g_edge_h(x0h, q.x, __int_as_float(q.y), lane, ax, ay);
        ++j;
    }
    for (; j + 8 <= re; j += 8) {
        int4 p0 = *(const int4*)(ep + j);
        int4 p1 = *(const int4*)(ep + j + 2);
        int4 p2 = *(const int4*)(ep + j + 4);
        int4 p3 = *(const int4*)(ep + j + 6);
        g_pair(x0h, p0, lane, ax, ay);
        g_pair(x0h, p1, lane, ax, ay);
        g_pair(x0h, p2, lane, ax, ay);
        g_pair(x0h, p3, lane, ax, ay);
    }
    if (j + 4 <= re) {
        int4 p0 = *(const int4*)(ep + j);
        int4 p1 = *(const int4*)(ep + j + 2);
        g_pair(x0h, p0, lane, ax, ay);
        g_pair(x0h, p1, lane, ax, ay);
        j += 4;
    }
    if (j + 2 <= re) {
        int4 p0 = *(const int4*)(ep + j);
        g_pair(x0h, p0, lane, ax, ay);
        j += 2;
    }
    if (j < re) {
        int2 q = ep[j];
        g_edge_h(x0h, q.x, __int_as_float(q.y), lane, ax, ay);
    }
    g_edge_h(x0h, wid, wd, lane, ax, ay);       // self-loop
    float sx = wd * ax, sy = wd * ay;
    u16 h0 = f2bf(sx), h1 = f2bf(sy);
    u16 l0 = f2bf(sx - bf2f(h0)), l1 = f2bf(sy - bf2f(h1));
    unsigned* orow = (unsigned*)(out + ((size_t)wid << 8));
    orow[lane]      = (unsigned)h0 | ((unsigned)h1 << 16);
    orow[64 + lane] = (unsigned)l0 | ((unsigned)l1 << 16);
}

// ---------------------------------------------------------------------------
// Fused GEMM chain, mixed precision:
//   stage A (conv, feeds 2 more layers): split-bf16, 3 MFMA/product
//   stages B/C: single f16 MFMA (error ~1e-3 << absmax 0.0156)
// LDS 26,112 B -> 6 blocks/CU (24 waves/CU, 2x the latency hiding of R5).
//   rs (f16 [32][136]) @0 ; ag_hi/ag_lo (bf16 [32][136]) @4352/@8704 ;
//   hs (f16 [32][264]) @4352 overlays ag (dead after stage A).
// A-frag: row = lane&15, k-slot = (lane>>4)*8+j; C/D: col = lane&15,
// row = (lane>>4)*4 + reg (m89/m91-verified).
// ---------------------------------------------------------------------------
__global__ __launch_bounds__(256, 6) void k_fmfma(
        const float* __restrict__ x0, const u16* __restrict__ wp,
        const float* __restrict__ bc, const float* __restrict__ b1,
        const float* __restrict__ b2, float* out) {
    __shared__ __align__(16) u16 sm[13056];
    u16* rs_   = sm;              // [32][136] f16
    u16* ag_hi = sm + 4352;       // [32][136] bf16
    u16* ag_lo = sm + 8704;
    u16* hs    = sm + 4352;       // [32][264] f16, overlays ag

    int row0 = blockIdx.x * TM;
    int t = threadIdx.x;
    int w = t >> 6;               // wave 0..3
    int l = t & 63;
    int lr = l & 15;              // A-frag row / C col
    int lg = l >> 4;              // k-group / C row-group

    // ---- phase 0: copy packed AGG planes (32 rows x 512 B) into LDS ----
#pragma unroll
    for (int it = 0; it < 4; ++it) {
        int idx = it * 256 + t;
        int r = idx >> 5, q = idx & 31;
        uint4 v = *(const uint4*)((const char*)out +
                                  ((size_t)(row0 + r) << 10) + (q << 4));
        u16* dst = (q < 16) ? (ag_hi + r * 136 + (q << 3))
                            : (ag_lo + r * 136 + ((q - 16) << 3));
        *(uint4*)dst = v;
    }
    __syncthreads();

    // ---- stage A: conv = ag@Wc (32x128, split-bf16); nt in {2w,2w+1} ----
    {
        f32x4 acc[2][2];
#pragma unroll
        for (int mi = 0; mi < 2; ++mi)
#pragma unroll
            for (int ni = 0; ni < 2; ++ni) acc[mi][ni] = (f32x4){0.f, 0.f, 0.f, 0.f};
#pragma unroll
        for (int kt = 0; kt < 4; ++kt) {
            int ka = kt * 32 + lg * 8;
            s16x8 a0h = *(const s16x8*)(ag_hi + lr * 136 + ka);
            s16x8 a0l = *(const s16x8*)(ag_lo + lr * 136 + ka);
            s16x8 a1h = *(const s16x8*)(ag_hi + (16 + lr) * 136 + ka);
            s16x8 a1l = *(const s16x8*)(ag_lo + (16 + lr) * 136 + ka);
#pragma unroll
            for (int ni = 0; ni < 2; ++ni) {
                int nt = 2 * w + ni;
                const u16* bp = wp + (kt * 8 + nt) * 1024 + l * 8;
                s16x8 bh = *(const s16x8*)(bp);
                s16x8 bl = *(const s16x8*)(bp + 512);
                acc[0][ni] = __builtin_amdgcn_mfma_f32_16x16x32_bf16(a0h, bl, acc[0][ni], 0, 0, 0);
                acc[0][ni] = __builtin_amdgcn_mfma_f32_16x16x32_bf16(a0l, bh, acc[0][ni], 0, 0, 0);
                acc[0][ni] = __builtin_amdgcn_mfma_f32_16x16x32_bf16(a0h, bh, acc[0][ni], 0, 0, 0);
                acc[1][ni] = __builtin_amdgcn_mfma_f32_16x16x32_bf16(a1h, bl, acc[1][ni], 0, 0, 0);
                acc[1][ni] = __builtin_amdgcn_mfma_f32_16x16x32_bf16(a1l, bh, acc[1][ni], 0, 0, 0);
                acc[1][ni] = __builtin_amdgcn_mfma_f32_16x16x32_bf16(a1h, bh, acc[1][ni], 0, 0, 0);
            }
        }
        // epilogue: rs = relu(conv + bc) + x0 -> f16 plane
#pragma unroll
        for (int ni = 0; ni < 2; ++ni) {
            int col = (2 * w + ni) * 16 + lr;
            float bias = bc[col];
#pragma unroll
            for (int mi = 0; mi < 2; ++mi)
#pragma unroll
                for (int r = 0; r < 4; ++r) {
                    int row = mi * 16 + lg * 4 + r;
                    float v = acc[mi][ni][r] + bias;
                    v = fmaxf(v, 0.f) + x0[(size_t)(row0 + row) * Fn + col];
                    rs_[row * 136 + col] = f2h(v);
                }
        }
    }
    __syncthreads();   // ag reads done (hs may overlay); rs visible

    // ---- stage B: hs = leaky(rs@W1 + b1) (32x256, f16); nt in {4w..4w+3} ----
    {
        const u16* w1p = wp + 32768;
        f32x4 acc[2][4];
#pragma unroll
        for (int mi = 0; mi < 2; ++mi)
#pragma unroll
            for (int ni = 0; ni < 4; ++ni) acc[mi][ni] = (f32x4){0.f, 0.f, 0.f, 0.f};
#pragma unroll
        for (int kt = 0; kt < 4; ++kt) {
            int ka = kt * 32 + lg * 8;
            f16x8 a0 = *(const f16x8*)(rs_ + lr * 136 + ka);
            f16x8 a1 = *(const f16x8*)(rs_ + (16 + lr) * 136 + ka);
#pragma unroll
            for (int ni = 0; ni < 4; ++ni) {
                int nt = 4 * w + ni;
                f16x8 b = *(const f16x8*)(w1p + (kt * 16 + nt) * 512 + l * 8);
                acc[0][ni] = __builtin_amdgcn_mfma_f32_16x16x32_f16(a0, b, acc[0][ni], 0, 0, 0);
                acc[1][ni] = __builtin_amdgcn_mfma_f32_16x16x32_f16(a1, b, acc[1][ni], 0, 0, 0);
            }
        }
#pragma unroll
        for (int ni = 0; ni < 4; ++ni) {
            int col = (4 * w + ni) * 16 + lr;
            float bias = b1[col];
#pragma unroll
            for (int mi = 0; mi < 2; ++mi)
#pragma unroll
                for (int r = 0; r < 4; ++r) {
                    int row = mi * 16 + lg * 4 + r;
                    float v = acc[mi][ni][r] + bias;
                    v = v > 0.f ? v : 0.01f * v;
                    hs[row * 264 + col] = f2h(v);
                }
        }
    }
    __syncthreads();

    // ---- stage C: out = leaky(hs@W2 + b2) (32x256, f16), K=256 ----
    {
        const u16* w2p = wp + 65536;
        f32x4 acc[2][4];
#pragma unroll
        for (int mi = 0; mi < 2; ++mi)
#pragma unroll
            for (int ni = 0; ni < 4; ++ni) acc[mi][ni] = (f32x4){0.f, 0.f, 0.f, 0.f};
#pragma unroll
        for (int kt = 0; kt < 8; ++kt) {
            int ka = kt * 32 + lg * 8;
            f16x8 a0 = *(const f16x8*)(hs + lr * 264 + ka);
            f16x8 a1 = *(const f16x8*)(hs + (16 + lr) * 264 + ka);
#pragma unroll
            for (int ni = 0; ni < 4; ++ni) {
                int nt = 4 * w + ni;
                f16x8 b = *(const f16x8*)(w2p + (kt * 16 + nt) * 512 + l * 8);
                acc[0][ni] = __builtin_amdgcn_mfma_f32_16x16x32_f16(a0, b, acc[0][ni], 0, 0, 0);
                acc[1][ni] = __builtin_amdgcn_mfma_f32_16x16x32_f16(a1, b, acc[1][ni], 0, 0, 0);
            }
        }
#pragma unroll
        for (int ni = 0; ni < 4; ++ni) {
            int col = (4 * w + ni) * 16 + lr;
            float bias = b2[col];
#pragma unroll
            for (int mi = 0; mi < 2; ++mi)
#pragma unroll
                for (int r = 0; r < 4; ++r) {
                    int row = mi * 16 + lg * 4 + r;
                    float v = acc[mi][ni][r] + bias;
                    v = v > 0.f ? v : 0.01f * v;
                    out[((size_t)(row0 + row) << 8) + col] = v;
                }
        }
    }
}

// ---------------------------------------------------------------------------
// Full fallback (tiny workspace): float degree + atomic scatter + f32 fused.
// ---------------------------------------------------------------------------
__global__ void k_canary(float* out) {
    if (threadIdx.x == 0 && blockIdx.x == 0) out[4] = 1000.0f;
}
__global__ void k_deg_init(float* __restrict__ deg) {
    int i = blockIdx.x * blockDim.x + threadIdx.x;
    if (i < NROW) deg[i] = 1.0f;
}
__global__ void k_deg_count(const int* __restrict__ e, float* __restrict__ deg) {
    bool i64 = edge_is_i64(e);
    int i = blockIdx.x * blockDim.x + threadIdx.x;
    if (i >= NEDGE) return;
    int b = i / En, k = i - b * En;
    int dst = eidx(e, (long long)(b * 2 + 1) * En + k, i64);
    if ((unsigned)dst < Nn) atomicAdd(&deg[b * Nn + dst], 1.0f);
}
__global__ void k_dinv(float* __restrict__ deg) {
    int i = blockIdx.x * blockDim.x + threadIdx.x;
    if (i < NROW) deg[i] = rsqrtf(deg[i]);
}
__global__ void k_agg_init(const float* __restrict__ x0,
                           const float* __restrict__ dinv,
                           float* __restrict__ out) {
    int i = blockIdx.x * blockDim.x + threadIdx.x;
    if (i >= NROW * Fn) return;
    int r = i >> 7;
    int c = i & 127;
    float dv = dinv[r];
    out[((size_t)r << 8) + c] = dv * dv * x0[i];
}
__global__ void k_scatter(const int* __restrict__ e,
                          const float* __restrict__ dinv,
                          const float* __restrict__ x0,
                          float* __restrict__ out) {
    bool i64 = edge_is_i64(e);
    long long gid = (long long)blockIdx.x * blockDim.x + threadIdx.x;
    int eid = (int)(gid >> 6);
    int lane = (int)(gid & 63);
    if (eid >= NEDGE) return;
    int b = eid / En, k = eid - b * En;
    int src = eidx(e, (long long)(b * 2) * En + k, i64);
    int dst = eidx(e, (long long)(b * 2 + 1) * En + k, i64);
    if ((unsigned)src >= Nn || (unsigned)dst >= Nn) return;
    float nrm = dinv[b * Nn + src] * dinv[b * Nn + dst];
    const float2 vf =
        *(const float2*)(x0 + ((size_t)(b * Nn + src) << 7) + 2 * lane);
    float* p = out + ((size_t)(b * Nn + dst) << 8) + 2 * lane;
    atomicAdd(p, nrm * vf.x);
    atomicAdd(p + 1, nrm * vf.y);
}

__global__ __launch_bounds__(256, 3) void k_fused(
        const float* __restrict__ x0,
        const float* __restrict__ Wc, const float* __restrict__ bc,
        const float* __restrict__ W1, const float* __restrict__ b1,
        const float* __restrict__ W2, const float* __restrict__ b2,
        float* out) {
    __shared__ float smem[12352];
    float (*rs)[Fn + 1] = (float (*)[Fn + 1])smem;
    float (*ag)[Fn + 1] = (float (*)[Fn + 1])(smem + 4128);
    float (*hs)[Hn + 1] = (float (*)[Hn + 1])(smem + 4128);

    int row0 = blockIdx.x * TM;
    int t = threadIdx.x;
    int tx = t & 31;
    int ty = t >> 5;
    int ra = ty * 4;

    for (int i = t; i < TM * Fn; i += 256) {
        int r = i >> 7, c = i & 127;
        ag[r][c] = out[((size_t)(row0 + r) << 8) + c];
    }
    __syncthreads();
    {
        float acc[4][4] = {};
#pragma unroll 4
        for (int k = 0; k < Fn; ++k) {
            float a0 = ag[ra + 0][k], a1 = ag[ra + 1][k],
                  a2 = ag[ra + 2][k], a3 = ag[ra + 3][k];
            const float4 b = *(const float4*)(Wc + k * Fn + tx * 4);
            acc[0][0] = fmaf(a0, b.x, acc[0][0]); acc[0][1] = fmaf(a0, b.y, acc[0][1]);
            acc[0][2] = fmaf(a0, b.z, acc[0][2]); acc[0][3] = fmaf(a0, b.w, acc[0][3]);
            acc[1][0] = fmaf(a1, b.x, acc[1][0]); acc[1][1] = fmaf(a1, b.y, acc[1][1]);
            acc[1][2] = fmaf(a1, b.z, acc[1][2]); acc[1][3] = fmaf(a1, b.w, acc[1][3]);
            acc[2][0] = fmaf(a2, b.x, acc[2][0]); acc[2][1] = fmaf(a2, b.y, acc[2][1]);
            acc[2][2] = fmaf(a2, b.z, acc[2][2]); acc[2][3] = fmaf(a2, b.w, acc[2][3]);
            acc[3][0] = fmaf(a3, b.x, acc[3][0]); acc[3][1] = fmaf(a3, b.y, acc[3][1]);
            acc[3][2] = fmaf(a3, b.z, acc[3][2]); acc[3][3] = fmaf(a3, b.w, acc[3][3]);
        }
        const float4 bcv = *(const float4*)(bc + tx * 4);
        __syncthreads();
#pragma unroll
        for (int i = 0; i < 4; ++i) {
            const float4 xv =
                *(const float4*)(x0 + (size_t)(row0 + ra + i) * Fn + tx * 4);
            rs[ra + i][tx * 4 + 0] = fmaxf(acc[i][0] + bcv.x, 0.f) + xv.x;
            rs[ra + i][tx * 4 + 1] = fmaxf(acc[i][1] + bcv.y, 0.f) + xv.y;
            rs[ra + i][tx * 4 + 2] = fmaxf(acc[i][2] + bcv.z, 0.f) + xv.z;
            rs[ra + i][tx * 4 + 3] = fmaxf(acc[i][3] + bcv.w, 0.f) + xv.w;
        }
    }
    __syncthreads();
    {
        float acc[4][8] = {};
#pragma unroll 2
        for (int k = 0; k < Fn; ++k) {
            float a0 = rs[ra + 0][k], a1 = rs[ra + 1][k],
                  a2 = rs[ra + 2][k], a3 = rs[ra + 3][k];
            const float4 p0 = *(const float4*)(W1 + k * Hn + tx * 8);
            const float4 p1 = *(const float4*)(W1 + k * Hn + tx * 8 + 4);
#pragma unroll
            for (int i = 0; i < 4; ++i) {
                float a = (i == 0) ? a0 : (i == 1) ? a1 : (i == 2) ? a2 : a3;
                acc[i][0] = fmaf(a, p0.x, acc[i][0]); acc[i][1] = fmaf(a, p0.y, acc[i][1]);
                acc[i][2] = fmaf(a, p0.z, acc[i][2]); acc[i][3] = fmaf(a, p0.w, acc[i][3]);
                acc[i][4] = fmaf(a, p1.x, acc[i][4]); acc[i][5] = fmaf(a, p1.y, acc[i][5]);
                acc[i][6] = fmaf(a, p1.z, acc[i][6]); acc[i][7] = fmaf(a, p1.w, acc[i][7]);
            }
        }
        const float4 b1a = *(const float4*)(b1 + tx * 8);
        const float4 b1b = *(const float4*)(b1 + tx * 8 + 4);
        float bias[8] = {b1a.x, b1a.y, b1a.z, b1a.w, b1b.x, b1b.y, b1b.z, b1b.w};
#pragma unroll
        for (int i = 0; i < 4; ++i)
#pragma unroll
            for (int j = 0; j < 8; ++j) {
                float h = acc[i][j] + bias[j];
                hs[ra + i][tx * 8 + j] = h > 0.f ? h : 0.01f * h;
            }
    }
    __syncthreads();
    {
        float acc[4][8] = {};
#pragma unroll 2
        for (int k = 0; k < Hn; ++k) {
            float a0 = hs[ra + 0][k], a1 = hs[ra + 1][k],
                  a2 = hs[ra + 2][k], a3 = hs[ra + 3][k];
            const float4 p0 = *(const float4*)(W2 + k * Hn + tx * 8);
            const float4 p1 = *(const float4*)(W2 + k * Hn + tx * 8 + 4);
#pragma unroll
            for (int i = 0; i < 4; ++i) {
                float a = (i == 0) ? a0 : (i == 1) ? a1 : (i == 2) ? a2 : a3;
                acc[i][0] = fmaf(a, p0.x, acc[i][0]); acc[i][1] = fmaf(a, p0.y, acc[i][1]);
                acc[i][2] = fmaf(a, p0.z, acc[i][2]); acc[i][3] = fmaf(a, p0.w, acc[i][3]);
                acc[i][4] = fmaf(a, p1.x, acc[i][4]); acc[i][5] = fmaf(a, p1.y, acc[i][5]);
                acc[i][6] = fmaf(a, p1.z, acc[i][6]); acc[i][7] = fmaf(a, p1.w, acc[i][7]);
            }
        }
        const float4 b2a = *(const float4*)(b2 + tx * 8);
        const float4 b2b = *(const float4*)(b2 + tx * 8 + 4);
        float bias[8] = {b2a.x, b2a.y, b2a.z, b2a.w, b2b.x, b2b.y, b2b.z, b2b.w};
#pragma unroll
        for (int i = 0; i < 4; ++i) {
            float o[8];
#pragma unroll
            for (int j = 0; j < 8; ++j) {
                float v = acc[i][j] + bias[j];
                o[j] = v > 0.f ? v : 0.01f * v;
            }
            float* dst = out + ((size_t)(row0 + ra + i) << 8) + tx * 8;
            *(float4*)(dst)     = make_float4(o[0], o[1], o[2], o[3]);
            *(float4*)(dst + 4) = make_float4(o[4], o[5], o[6], o[7]);
        }
    }
}

// ---------------------------------------------------------------------------
extern "C" void kernel_launch(void* const* d_in, const int* in_sizes, int n_in,
                              void* d_out, int out_size, void* d_ws, size_t ws_size,
                              hipStream_t stream) {
    const float* x0 = (const float*)d_in[0];
    const int*   ed = (const int*)d_in[1];
    const float* Wc = (const float*)d_in[2];
    const float* bc = (const float*)d_in[3];
    const float* W1 = (const float*)d_in[4];
    const float* b1 = (const float*)d_in[5];
    const float* W2 = (const float*)d_in[6];
    const float* b2 = (const float*)d_in[7];

    float* out = (float*)d_out;
    int*   wsi = (int*)d_ws;
    float* wsf = (float*)d_ws;

    if (ws_size >= WS_NEED) {
        int*    degi      = wsi;                 // -> dinv (f32) after scan3
        float*  dinv      = wsf;
        int*    row_start = wsi + OFF_RS;
        int*    cursor    = wsi + OFF_CUR;
        int*    bsum      = wsi + OFF_BS;
        int*    boff      = wsi + OFF_BO;
        int2*   ep        = (int2*)(wsi + OFF_EP);
        u16*    wp        = (u16*)(wsi + WSI_END);
        __half* x0h       = (__half*)((char*)d_ws + X0H_OFF);

        k_prep<<<10448, 256, 0, stream>>>(degi, x0h, x0, out, Wc, W1, W2, wp);
        k_deg2<<<NEDGE / 2 / 256, 256, 0, stream>>>(ed, degi);
        k_scan1<<<313, 256, 0, stream>>>(degi, row_start, bsum);
        k_scan2<<<1, 512, 0, stream>>>(bsum, boff, row_start);
        k_scan3<<<313, 256, 0, stream>>>(degi, dinv, row_start, boff, cursor);
        k_bin2<<<NEDGE / 2 / 256, 256, 0, stream>>>(ed, dinv, cursor, ep);
        k_gather3<<<NROW / 4, 256, 0, stream>>>(
            x0h, dinv, row_start, cursor, ep, out);
        k_fmfma<<<NROW / TM, 256, 0, stream>>>(x0, wp, bc, b1, b2, out);
    } else {
        float* deg = wsf;
        k_canary<<<1, 64, 0, stream>>>(out);
        k_deg_init<<<(NROW + 255) / 256, 256, 0, stream>>>(deg);
        k_deg_count<<<(NEDGE + 255) / 256, 256, 0, stream>>>(ed, deg);
        k_dinv<<<(NROW + 255) / 256, 256, 0, stream>>>(deg);
        k_agg_init<<<(NROW * Fn + 255) / 256, 256, 0, stream>>>(x0, deg, out);
        long long sthreads = (long long)NEDGE * 64;
        k_scatter<<<(int)((sthreads + 255) / 256), 256, 0, stream>>>(ed, deg, x0, out);
        k_fused<<<NROW / TM, 256, 0, stream>>>(x0, Wc, bc, W1, b1, W2, b2, out);
    }
}

// Round 7
// 333.090 us; speedup vs baseline: 1.2494x; 1.0383x over previous
//
#include <hip/hip_runtime.h>
#include <hip/hip_bf16.h>
#include <hip/hip_fp16.h>

// Problem constants: B=8, N=10000, E=160000, F=128, H=256
#define Bn 8
#define Nn 10000
#define En 160000
#define Fn 128
#define Hn 256
#define NROW (Bn * Nn)     // 80,000
#define NEDGE (Bn * En)    // 1,280,000
#define TM 32              // rows per block in fused epilogue

// Workspace layout (ints):
//   [0,80000)            deg (int) -> dinv (f32) after k_scan3
//   [80000,160001)       row_start
//   [160004,240004)      cursor
//   [240004,240317)      bsum (313)
//   [240320,240832)      boff (512)
//   [240832,2800832)     ep: int2 {src, bits(dinv[src])} per edge, CSR order
//   then 262,144 B packed weights (u16): Wc split-bf16 [0,32768),
//        W1 f16 [32768,65536), W2 f16 [65536,131072)
//   then 20,480,000 B x0 as f16 [NROW][128].
// out row layout (1024 B): [0,256)=AGG hi bf16, [256,512)=AGG lo bf16
//   (gather writes; k_fmfma stage C overwrites all 1024 B).
// R7: k_deg2/k_bin2 XCD-partitioned by graph (blockIdx&7 = graph = XCD via
//   round-robin dispatch): each XCD's L2 owns one graph's ep segment
//   (1.28 MB) + cursor/deg slice (40 KB) -> kills the 8x write
//   amplification (R6 counters: WRITE_SIZE 81 MB for a 10.2 MB array,
//   cross-XCD line ping-pong) and keeps scatter atomics on-die.
#define OFF_RS   80000
#define OFF_CUR  160004
#define OFF_BS   240004
#define OFF_BO   240320
#define OFF_EP   240832
#define WSI_END  2800832
#define WP_U16   131072
#define WP_BYTES ((size_t)WP_U16 * 2)                 // 262,144
#define X0H_BYTES ((size_t)NROW * Fn * 2)             // 20,480,000
#define X0H_OFF  ((size_t)WSI_END * 4 + WP_BYTES)     // 11,465,472
#define WS_NEED  (X0H_OFF + X0H_BYTES)                // 31,945,472

typedef unsigned short u16;
typedef __attribute__((ext_vector_type(8))) short s16x8;
typedef __attribute__((ext_vector_type(8))) _Float16 f16x8;
typedef __attribute__((ext_vector_type(4))) float f32x4;

__device__ __forceinline__ u16 f2bf(float x) {           // RNE f32->bf16
    unsigned u = __float_as_uint(x);
    u += 0x7FFF + ((u >> 16) & 1);
    return (u16)(u >> 16);
}
__device__ __forceinline__ float bf2f(u16 h) {
    return __uint_as_float((unsigned)h << 16);
}
__device__ __forceinline__ u16 f2h(float x) {            // RNE f32->f16 bits
    _Float16 h = (_Float16)x;
    return *(u16*)&h;
}

__device__ __forceinline__ bool edge_is_i64(const int* e) {
    return e[1] == 0 && e[3] == 0;
}
__device__ __forceinline__ int eidx(const int* e, long long i, bool i64) {
    return i64 ? e[2 * i] : e[i];
}

// ---------------------------------------------------------------------------
// k_prep: deg=1 + canary + x0->f16 table (blocks 0..9999) and weight pack
// (blocks 10000..10447).
// Weight pack k-map: k = kt*32 + (l>>4)*8 + j (same map as A-frags).
// ---------------------------------------------------------------------------
__global__ void k_prep(int* __restrict__ deg, __half* __restrict__ x0h,
                       const float* __restrict__ x0, float* __restrict__ out,
                       const float* __restrict__ Wc, const float* __restrict__ W1,
                       const float* __restrict__ W2, u16* __restrict__ wp) {
    if (blockIdx.x < 10000) {
        int i = blockIdx.x * 256 + threadIdx.x;     // < NROW*32
        if (i < NROW) deg[i] = 1;
        if (i == 0) out[4] = 1000.0f;               // erased by k_gather3
        int r = i >> 5, g = i & 31;
        float4 v = *(const float4*)(x0 + ((size_t)r << 7) + (g << 2));
        __half2 a = __floats2half2_rn(v.x, v.y);
        __half2 b = __floats2half2_rn(v.z, v.w);
        uint2 u;
        u.x = *(unsigned*)&a;
        u.y = *(unsigned*)&b;
        *(uint2*)((char*)x0h + ((size_t)r << 8) + (g << 3)) = u;
    } else {
        int i = (blockIdx.x - 10000) * 256 + threadIdx.x;   // < 114688
        if (i < 16384) {                 // Wc: split-bf16, NT=8
            int j = i & 7, l = (i >> 3) & 63;
            int nt = (i >> 9) & 7, kt = i >> 12;
            int k = kt * 32 + (l >> 4) * 8 + j;
            int n = nt * 16 + (l & 15);
            float v = Wc[(size_t)k * Fn + n];
            u16 hi = f2bf(v);
            u16 lo = f2bf(v - bf2f(hi));
            int o = (kt * 8 + nt) * 1024 + l * 8 + j;
            wp[o] = hi;
            wp[o + 512] = lo;
        } else if (i < 49152) {          // W1: f16 single, NT=16, kt<4
            int idx = i - 16384;
            int j = idx & 7, l = (idx >> 3) & 63;
            int nt = (idx >> 9) & 15, kt = idx >> 13;
            int k = kt * 32 + (l >> 4) * 8 + j;
            int n = nt * 16 + (l & 15);
            wp[32768 + (kt * 16 + nt) * 512 + l * 8 + j] =
                f2h(W1[(size_t)k * Hn + n]);
        } else if (i < 114688) {         // W2: f16 single, NT=16, kt<8
            int idx = i - 49152;
            int j = idx & 7, l = (idx >> 3) & 63;
            int nt = (idx >> 9) & 15, kt = idx >> 13;
            int k = kt * 32 + (l >> 4) * 8 + j;
            int n = nt * 16 + (l & 15);
            wp[65536 + (kt * 16 + nt) * 512 + l * 8 + j] =
                f2h(W2[(size_t)k * Hn + n]);
        }
    }
}

// ---------------------------------------------------------------------------
// Degree count, XCD-partitioned: graph = blockIdx&7 (round-robin -> one XCD
// per graph), 2 edges/thread. deg slice (40 KB) stays in that XCD's L2.
// ---------------------------------------------------------------------------
__global__ void k_deg2(const int* __restrict__ e, int* __restrict__ deg) {
    bool i64 = edge_is_i64(e);
    int b = blockIdx.x & 7;                          // graph == XCD
    int p = (blockIdx.x >> 3) * 256 + threadIdx.x;   // pair idx within graph
    if (p >= En / 2) return;
    int kk = p * 2;
    int d0, d1;
    if (i64) {
        int4 v = *(const int4*)(e + ((long long)(b * 2 + 1) * En + kk) * 2);
        d0 = v.x; d1 = v.z;
    } else {
        int2 v = *(const int2*)(e + (long long)(b * 2 + 1) * En + kk);
        d0 = v.x; d1 = v.y;
    }
    if ((unsigned)d0 < Nn) atomicAdd(&deg[b * Nn + d0], 1);
    if ((unsigned)d1 < Nn) atomicAdd(&deg[b * Nn + d1], 1);
}

// ---------------------------------------------------------------------------
// Exclusive scan of in-degree over 80,000 rows, 3 kernels.
// ---------------------------------------------------------------------------
__global__ void k_scan1(const int* __restrict__ deg,
                        int* __restrict__ row_start, int* __restrict__ bsum) {
    __shared__ int s[256];
    int i = blockIdx.x * 256 + threadIdx.x;
    int v = (i < NROW) ? (deg[i] - 1) : 0;
    s[threadIdx.x] = v;
    __syncthreads();
    for (int off = 1; off < 256; off <<= 1) {
        int t = (threadIdx.x >= off) ? s[threadIdx.x - off] : 0;
        __syncthreads();
        s[threadIdx.x] += t;
        __syncthreads();
    }
    if (i < NROW) row_start[i] = s[threadIdx.x] - v;
    if (threadIdx.x == 255) bsum[blockIdx.x] = s[255];
}

__global__ void k_scan2(const int* __restrict__ bsum, int* __restrict__ boff,
                        int* __restrict__ row_start) {
    __shared__ int s[512];
    int t = threadIdx.x;
    int v = (t < 313) ? bsum[t] : 0;
    s[t] = v;
    __syncthreads();
    for (int off = 1; off < 512; off <<= 1) {
        int u = (t >= off) ? s[t - off] : 0;
        __syncthreads();
        s[t] += u;
        __syncthreads();
    }
    boff[t] = s[t] - v;
    if (t == 511) row_start[NROW] = s[511];
}

__global__ void k_scan3(int* __restrict__ degi, float* __restrict__ dinvf,
                        int* __restrict__ row_start,
                        const int* __restrict__ boff, int* __restrict__ cursor) {
    int i = blockIdx.x * blockDim.x + threadIdx.x;
    if (i >= NROW) return;
    int v = row_start[i] + boff[i >> 8];
    row_start[i] = v;
    cursor[i] = v;
    float d = (float)degi[i];
    dinvf[i] = rsqrtf(d);
}

// ---------------------------------------------------------------------------
// Counting-sort, XCD-partitioned by graph; 8B fused (src, dinv-bits) records.
// Graph b's ep segment (~1.28 MB) + cursor slice live in XCD b's L2 only ->
// each 64B line written back once.
// ---------------------------------------------------------------------------
__global__ void k_bin2(const int* __restrict__ e, const float* __restrict__ dinv,
                       int* __restrict__ cursor, int2* __restrict__ ep) {
    bool i64 = edge_is_i64(e);
    int b = blockIdx.x & 7;                          // graph == XCD
    int p = (blockIdx.x >> 3) * 256 + threadIdx.x;   // pair idx within graph
    if (p >= En / 2) return;
    int kk = p * 2;
    int s0, s1, d0, d1;
    if (i64) {
        int4 sv = *(const int4*)(e + ((long long)(b * 2) * En + kk) * 2);
        int4 dv = *(const int4*)(e + ((long long)(b * 2 + 1) * En + kk) * 2);
        s0 = sv.x; s1 = sv.z; d0 = dv.x; d1 = dv.z;
    } else {
        int2 sv = *(const int2*)(e + (long long)(b * 2) * En + kk);
        int2 dv = *(const int2*)(e + (long long)(b * 2 + 1) * En + kk);
        s0 = sv.x; s1 = sv.y; d0 = dv.x; d1 = dv.y;
    }
    if ((unsigned)s0 < Nn && (unsigned)d0 < Nn) {
        int g = b * Nn + s0;
        int pos = atomicAdd(&cursor[b * Nn + d0], 1);
        ep[pos] = make_int2(g, __float_as_int(dinv[g]));
    }
    if ((unsigned)s1 < Nn && (unsigned)d1 < Nn) {
        int g = b * Nn + s1;
        int pos = atomicAdd(&cursor[b * Nn + d1], 1);
        ep[pos] = make_int2(g, __float_as_int(dinv[g]));
    }
}

// ---------------------------------------------------------------------------
// Gather: one wave per row, 2 cols/lane, zero LDS (full occupancy hides L2
// latency — R4 lesson). Reads f16 x0h (2.56 MB/graph, XCD-L2-resident via
// chunking) + 8B edge records; writes AGG bf16 hi/lo planes to out[0,512).
// ---------------------------------------------------------------------------
__device__ __forceinline__ void g_edge_h(const __half* __restrict__ x0h, int s,
                                         float w, int lane, float& ax, float& ay) {
    __half2 h = *(const __half2*)(x0h + ((size_t)s << 7) + 2 * lane);
    float2 v = __half22float2(h);
    ax = fmaf(w, v.x, ax);
    ay = fmaf(w, v.y, ay);
}
__device__ __forceinline__ void g_pair(const __half* __restrict__ x0h,
                                       int4 pq, int lane, float& ax, float& ay) {
    g_edge_h(x0h, pq.x, __int_as_float(pq.y), lane, ax, ay);
    g_edge_h(x0h, pq.z, __int_as_float(pq.w), lane, ax, ay);
}

__global__ __launch_bounds__(256) void k_gather3(
        const __half* __restrict__ x0h, const float* __restrict__ dinv,
        const int* __restrict__ row_start, const int* __restrict__ row_end,
        const int2* __restrict__ ep, float* __restrict__ out) {
    // XCD chunking: 20,000 blocks = 8 * 2500; chunk per XCD = one graph.
    int sb = (blockIdx.x & 7) * 2500 + (blockIdx.x >> 3);
    int wid = ((sb * 256 + (int)threadIdx.x) >> 6);
    int lane = threadIdx.x & 63;
    if (wid >= NROW) return;
    int rs = row_start[wid], re = row_end[wid];
    float wd = dinv[wid];
    float ax = 0.f, ay = 0.f;
    int j = rs;
    if (j < re && (j & 1)) {            // peel to int4 alignment
        int2 q = ep[j];
        g_edge_h(x0h, q.x, __int_as_float(q.y), lane, ax, ay);
        ++j;
    }
    for (; j + 8 <= re; j += 8) {
        int4 p0 = *(const int4*)(ep + j);
        int4 p1 = *(const int4*)(ep + j + 2);
        int4 p2 = *(const int4*)(ep + j + 4);
        int4 p3 = *(const int4*)(ep + j + 6);
        g_pair(x0h, p0, lane, ax, ay);
        g_pair(x0h, p1, lane, ax, ay);
        g_pair(x0h, p2, lane, ax, ay);
        g_pair(x0h, p3, lane, ax, ay);
    }
    if (j + 4 <= re) {
        int4 p0 = *(const int4*)(ep + j);
        int4 p1 = *(const int4*)(ep + j + 2);
        g_pair(x0h, p0, lane, ax, ay);
        g_pair(x0h, p1, lane, ax, ay);
        j += 4;
    }
    if (j + 2 <= re) {
        int4 p0 = *(const int4*)(ep + j);
        g_pair(x0h, p0, lane, ax, ay);
        j += 2;
    }
    if (j < re) {
        int2 q = ep[j];
        g_edge_h(x0h, q.x, __int_as_float(q.y), lane, ax, ay);
    }
    g_edge_h(x0h, wid, wd, lane, ax, ay);       // self-loop
    float sx = wd * ax, sy = wd * ay;
    u16 h0 = f2bf(sx), h1 = f2bf(sy);
    u16 l0 = f2bf(sx - bf2f(h0)), l1 = f2bf(sy - bf2f(h1));
    unsigned* orow = (unsigned*)(out + ((size_t)wid << 8));
    orow[lane]      = (unsigned)h0 | ((unsigned)h1 << 16);
    orow[64 + lane] = (unsigned)l0 | ((unsigned)l1 << 16);
}

// ---------------------------------------------------------------------------
// Fused GEMM chain, mixed precision:
//   stage A (conv, feeds 2 more layers): split-bf16, 3 MFMA/product
//   stages B/C: single f16 MFMA (error ~1e-3 << absmax 0.0156)
// LDS 26,112 B -> 6 blocks/CU (24 waves/CU).
//   rs (f16 [32][136]) @0 ; ag_hi/ag_lo (bf16 [32][136]) @4352/@8704 ;
//   hs (f16 [32][264]) @4352 overlays ag (dead after stage A).
// A-frag: row = lane&15, k-slot = (lane>>4)*8+j; C/D: col = lane&15,
// row = (lane>>4)*4 + reg (m89/m91-verified).
// ---------------------------------------------------------------------------
__global__ __launch_bounds__(256, 6) void k_fmfma(
        const float* __restrict__ x0, const u16* __restrict__ wp,
        const float* __restrict__ bc, const float* __restrict__ b1,
        const float* __restrict__ b2, float* out) {
    __shared__ __align__(16) u16 sm[13056];
    u16* rs_   = sm;              // [32][136] f16
    u16* ag_hi = sm + 4352;       // [32][136] bf16
    u16* ag_lo = sm + 8704;
    u16* hs    = sm + 4352;       // [32][264] f16, overlays ag

    int row0 = blockIdx.x * TM;
    int t = threadIdx.x;
    int w = t >> 6;               // wave 0..3
    int l = t & 63;
    int lr = l & 15;              // A-frag row / C col
    int lg = l >> 4;              // k-group / C row-group

    // ---- phase 0: copy packed AGG planes (32 rows x 512 B) into LDS ----
#pragma unroll
    for (int it = 0; it < 4; ++it) {
        int idx = it * 256 + t;
        int r = idx >> 5, q = idx & 31;
        uint4 v = *(const uint4*)((const char*)out +
                                  ((size_t)(row0 + r) << 10) + (q << 4));
        u16* dst = (q < 16) ? (ag_hi + r * 136 + (q << 3))
                            : (ag_lo + r * 136 + ((q - 16) << 3));
        *(uint4*)dst = v;
    }
    __syncthreads();

    // ---- stage A: conv = ag@Wc (32x128, split-bf16); nt in {2w,2w+1} ----
    {
        f32x4 acc[2][2];
#pragma unroll
        for (int mi = 0; mi < 2; ++mi)
#pragma unroll
            for (int ni = 0; ni < 2; ++ni) acc[mi][ni] = (f32x4){0.f, 0.f, 0.f, 0.f};
#pragma unroll
        for (int kt = 0; kt < 4; ++kt) {
            int ka = kt * 32 + lg * 8;
            s16x8 a0h = *(const s16x8*)(ag_hi + lr * 136 + ka);
            s16x8 a0l = *(const s16x8*)(ag_lo + lr * 136 + ka);
            s16x8 a1h = *(const s16x8*)(ag_hi + (16 + lr) * 136 + ka);
            s16x8 a1l = *(const s16x8*)(ag_lo + (16 + lr) * 136 + ka);
#pragma unroll
            for (int ni = 0; ni < 2; ++ni) {
                int nt = 2 * w + ni;
                const u16* bp = wp + (kt * 8 + nt) * 1024 + l * 8;
                s16x8 bh = *(const s16x8*)(bp);
                s16x8 bl = *(const s16x8*)(bp + 512);
                acc[0][ni] = __builtin_amdgcn_mfma_f32_16x16x32_bf16(a0h, bl, acc[0][ni], 0, 0, 0);
                acc[0][ni] = __builtin_amdgcn_mfma_f32_16x16x32_bf16(a0l, bh, acc[0][ni], 0, 0, 0);
                acc[0][ni] = __builtin_amdgcn_mfma_f32_16x16x32_bf16(a0h, bh, acc[0][ni], 0, 0, 0);
                acc[1][ni] = __builtin_amdgcn_mfma_f32_16x16x32_bf16(a1h, bl, acc[1][ni], 0, 0, 0);
                acc[1][ni] = __builtin_amdgcn_mfma_f32_16x16x32_bf16(a1l, bh, acc[1][ni], 0, 0, 0);
                acc[1][ni] = __builtin_amdgcn_mfma_f32_16x16x32_bf16(a1h, bh, acc[1][ni], 0, 0, 0);
            }
        }
        // epilogue: rs = relu(conv + bc) + x0 -> f16 plane
#pragma unroll
        for (int ni = 0; ni < 2; ++ni) {
            int col = (2 * w + ni) * 16 + lr;
            float bias = bc[col];
#pragma unroll
            for (int mi = 0; mi < 2; ++mi)
#pragma unroll
                for (int r = 0; r < 4; ++r) {
                    int row = mi * 16 + lg * 4 + r;
                    float v = acc[mi][ni][r] + bias;
                    v = fmaxf(v, 0.f) + x0[(size_t)(row0 + row) * Fn + col];
                    rs_[row * 136 + col] = f2h(v);
                }
        }
    }
    __syncthreads();   // ag reads done (hs may overlay); rs visible

    // ---- stage B: hs = leaky(rs@W1 + b1) (32x256, f16); nt in {4w..4w+3} ----
    {
        const u16* w1p = wp + 32768;
        f32x4 acc[2][4];
#pragma unroll
        for (int mi = 0; mi < 2; ++mi)
#pragma unroll
            for (int ni = 0; ni < 4; ++ni) acc[mi][ni] = (f32x4){0.f, 0.f, 0.f, 0.f};
#pragma unroll
        for (int kt = 0; kt < 4; ++kt) {
            int ka = kt * 32 + lg * 8;
            f16x8 a0 = *(const f16x8*)(rs_ + lr * 136 + ka);
            f16x8 a1 = *(const f16x8*)(rs_ + (16 + lr) * 136 + ka);
#pragma unroll
            for (int ni = 0; ni < 4; ++ni) {
                int nt = 4 * w + ni;
                f16x8 b = *(const f16x8*)(w1p + (kt * 16 + nt) * 512 + l * 8);
                acc[0][ni] = __builtin_amdgcn_mfma_f32_16x16x32_f16(a0, b, acc[0][ni], 0, 0, 0);
                acc[1][ni] = __builtin_amdgcn_mfma_f32_16x16x32_f16(a1, b, acc[1][ni], 0, 0, 0);
            }
        }
#pragma unroll
        for (int ni = 0; ni < 4; ++ni) {
            int col = (4 * w + ni) * 16 + lr;
            float bias = b1[col];
#pragma unroll
            for (int mi = 0; mi < 2; ++mi)
#pragma unroll
                for (int r = 0; r < 4; ++r) {
                    int row = mi * 16 + lg * 4 + r;
                    float v = acc[mi][ni][r] + bias;
                    v = v > 0.f ? v : 0.01f * v;
                    hs[row * 264 + col] = f2h(v);
                }
        }
    }
    __syncthreads();

    // ---- stage C: out = leaky(hs@W2 + b2) (32x256, f16), K=256 ----
    {
        const u16* w2p = wp + 65536;
        f32x4 acc[2][4];
#pragma unroll
        for (int mi = 0; mi < 2; ++mi)
#pragma unroll
            for (int ni = 0; ni < 4; ++ni) acc[mi][ni] = (f32x4){0.f, 0.f, 0.f, 0.f};
#pragma unroll
        for (int kt = 0; kt < 8; ++kt) {
            int ka = kt * 32 + lg * 8;
            f16x8 a0 = *(const f16x8*)(hs + lr * 264 + ka);
            f16x8 a1 = *(const f16x8*)(hs + (16 + lr) * 264 + ka);
#pragma unroll
            for (int ni = 0; ni < 4; ++ni) {
                int nt = 4 * w + ni;
                f16x8 b = *(const f16x8*)(w2p + (kt * 16 + nt) * 512 + l * 8);
                acc[0][ni] = __builtin_amdgcn_mfma_f32_16x16x32_f16(a0, b, acc[0][ni], 0, 0, 0);
                acc[1][ni] = __builtin_amdgcn_mfma_f32_16x16x32_f16(a1, b, acc[1][ni], 0, 0, 0);
            }
        }
#pragma unroll
        for (int ni = 0; ni < 4; ++ni) {
            int col = (4 * w + ni) * 16 + lr;
            float bias = b2[col];
#pragma unroll
            for (int mi = 0; mi < 2; ++mi)
#pragma unroll
                for (int r = 0; r < 4; ++r) {
                    int row = mi * 16 + lg * 4 + r;
                    float v = acc[mi][ni][r] + bias;
                    v = v > 0.f ? v : 0.01f * v;
                    out[((size_t)(row0 + row) << 8) + col] = v;
                }
        }
    }
}

// ---------------------------------------------------------------------------
// Full fallback (tiny workspace): float degree + atomic scatter + f32 fused.
// ---------------------------------------------------------------------------
__global__ void k_canary(float* out) {
    if (threadIdx.x == 0 && blockIdx.x == 0) out[4] = 1000.0f;
}
__global__ void k_deg_init(float* __restrict__ deg) {
    int i = blockIdx.x * blockDim.x + threadIdx.x;
    if (i < NROW) deg[i] = 1.0f;
}
__global__ void k_deg_count(const int* __restrict__ e, float* __restrict__ deg) {
    bool i64 = edge_is_i64(e);
    int i = blockIdx.x * blockDim.x + threadIdx.x;
    if (i >= NEDGE) return;
    int b = i / En, k = i - b * En;
    int dst = eidx(e, (long long)(b * 2 + 1) * En + k, i64);
    if ((unsigned)dst < Nn) atomicAdd(&deg[b * Nn + dst], 1.0f);
}
__global__ void k_dinv(float* __restrict__ deg) {
    int i = blockIdx.x * blockDim.x + threadIdx.x;
    if (i < NROW) deg[i] = rsqrtf(deg[i]);
}
__global__ void k_agg_init(const float* __restrict__ x0,
                           const float* __restrict__ dinv,
                           float* __restrict__ out) {
    int i = blockIdx.x * blockDim.x + threadIdx.x;
    if (i >= NROW * Fn) return;
    int r = i >> 7;
    int c = i & 127;
    float dv = dinv[r];
    out[((size_t)r << 8) + c] = dv * dv * x0[i];
}
__global__ void k_scatter(const int* __restrict__ e,
                          const float* __restrict__ dinv,
                          const float* __restrict__ x0,
                          float* __restrict__ out) {
    bool i64 = edge_is_i64(e);
    long long gid = (long long)blockIdx.x * blockDim.x + threadIdx.x;
    int eid = (int)(gid >> 6);
    int lane = (int)(gid & 63);
    if (eid >= NEDGE) return;
    int b = eid / En, k = eid - b * En;
    int src = eidx(e, (long long)(b * 2) * En + k, i64);
    int dst = eidx(e, (long long)(b * 2 + 1) * En + k, i64);
    if ((unsigned)src >= Nn || (unsigned)dst >= Nn) return;
    float nrm = dinv[b * Nn + src] * dinv[b * Nn + dst];
    const float2 vf =
        *(const float2*)(x0 + ((size_t)(b * Nn + src) << 7) + 2 * lane);
    float* p = out + ((size_t)(b * Nn + dst) << 8) + 2 * lane;
    atomicAdd(p, nrm * vf.x);
    atomicAdd(p + 1, nrm * vf.y);
}

__global__ __launch_bounds__(256, 3) void k_fused(
        const float* __restrict__ x0,
        const float* __restrict__ Wc, const float* __restrict__ bc,
        const float* __restrict__ W1, const float* __restrict__ b1,
        const float* __restrict__ W2, const float* __restrict__ b2,
        float* out) {
    __shared__ float smem[12352];
    float (*rs)[Fn + 1] = (float (*)[Fn + 1])smem;
    float (*ag)[Fn + 1] = (float (*)[Fn + 1])(smem + 4128);
    float (*hs)[Hn + 1] = (float (*)[Hn + 1])(smem + 4128);

    int row0 = blockIdx.x * TM;
    int t = threadIdx.x;
    int tx = t & 31;
    int ty = t >> 5;
    int ra = ty * 4;

    for (int i = t; i < TM * Fn; i += 256) {
        int r = i >> 7, c = i & 127;
        ag[r][c] = out[((size_t)(row0 + r) << 8) + c];
    }
    __syncthreads();
    {
        float acc[4][4] = {};
#pragma unroll 4
        for (int k = 0; k < Fn; ++k) {
            float a0 = ag[ra + 0][k], a1 = ag[ra + 1][k],
                  a2 = ag[ra + 2][k], a3 = ag[ra + 3][k];
            const float4 b = *(const float4*)(Wc + k * Fn + tx * 4);
            acc[0][0] = fmaf(a0, b.x, acc[0][0]); acc[0][1] = fmaf(a0, b.y, acc[0][1]);
            acc[0][2] = fmaf(a0, b.z, acc[0][2]); acc[0][3] = fmaf(a0, b.w, acc[0][3]);
            acc[1][0] = fmaf(a1, b.x, acc[1][0]); acc[1][1] = fmaf(a1, b.y, acc[1][1]);
            acc[1][2] = fmaf(a1, b.z, acc[1][2]); acc[1][3] = fmaf(a1, b.w, acc[1][3]);
            acc[2][0] = fmaf(a2, b.x, acc[2][0]); acc[2][1] = fmaf(a2, b.y, acc[2][1]);
            acc[2][2] = fmaf(a2, b.z, acc[2][2]); acc[2][3] = fmaf(a2, b.w, acc[2][3]);
            acc[3][0] = fmaf(a3, b.x, acc[3][0]); acc[3][1] = fmaf(a3, b.y, acc[3][1]);
            acc[3][2] = fmaf(a3, b.z, acc[3][2]); acc[3][3] = fmaf(a3, b.w, acc[3][3]);
        }
        const float4 bcv = *(const float4*)(bc + tx * 4);
        __syncthreads();
#pragma unroll
        for (int i = 0; i < 4; ++i) {
            const float4 xv =
                *(const float4*)(x0 + (size_t)(row0 + ra + i) * Fn + tx * 4);
            rs[ra + i][tx * 4 + 0] = fmaxf(acc[i][0] + bcv.x, 0.f) + xv.x;
            rs[ra + i][tx * 4 + 1] = fmaxf(acc[i][1] + bcv.y, 0.f) + xv.y;
            rs[ra + i][tx * 4 + 2] = fmaxf(acc[i][2] + bcv.z, 0.f) + xv.z;
            rs[ra + i][tx * 4 + 3] = fmaxf(acc[i][3] + bcv.w, 0.f) + xv.w;
        }
    }
    __syncthreads();
    {
        float acc[4][8] = {};
#pragma unroll 2
        for (int k = 0; k < Fn; ++k) {
            float a0 = rs[ra + 0][k], a1 = rs[ra + 1][k],
                  a2 = rs[ra + 2][k], a3 = rs[ra + 3][k];
            const float4 p0 = *(const float4*)(W1 + k * Hn + tx * 8);
            const float4 p1 = *(const float4*)(W1 + k * Hn + tx * 8 + 4);
#pragma unroll
            for (int i = 0; i < 4; ++i) {
                float a = (i == 0) ? a0 : (i == 1) ? a1 : (i == 2) ? a2 : a3;
                acc[i][0] = fmaf(a, p0.x, acc[i][0]); acc[i][1] = fmaf(a, p0.y, acc[i][1]);
                acc[i][2] = fmaf(a, p0.z, acc[i][2]); acc[i][3] = fmaf(a, p0.w, acc[i][3]);
                acc[i][4] = fmaf(a, p1.x, acc[i][4]); acc[i][5] = fmaf(a, p1.y, acc[i][5]);
                acc[i][6] = fmaf(a, p1.z, acc[i][6]); acc[i][7] = fmaf(a, p1.w, acc[i][7]);
            }
        }
        const float4 b1a = *(const float4*)(b1 + tx * 8);
        const float4 b1b = *(const float4*)(b1 + tx * 8 + 4);
        float bias[8] = {b1a.x, b1a.y, b1a.z, b1a.w, b1b.x, b1b.y, b1b.z, b1b.w};
#pragma unroll
        for (int i = 0; i < 4; ++i)
#pragma unroll
            for (int j = 0; j < 8; ++j) {
                float h = acc[i][j] + bias[j];
                hs[ra + i][tx * 8 + j] = h > 0.f ? h : 0.01f * h;
            }
    }
    __syncthreads();
    {
        float acc[4][8] = {};
#pragma unroll 2
        for (int k = 0; k < Hn; ++k) {
            float a0 = hs[ra + 0][k], a1 = hs[ra + 1][k],
                  a2 = hs[ra + 2][k], a3 = hs[ra + 3][k];
            const float4 p0 = *(const float4*)(W2 + k * Hn + tx * 8);
            const float4 p1 = *(const float4*)(W2 + k * Hn + tx * 8 + 4);
#pragma unroll
            for (int i = 0; i < 4; ++i) {
                float a = (i == 0) ? a0 : (i == 1) ? a1 : (i == 2) ? a2 : a3;
                acc[i][0] = fmaf(a, p0.x, acc[i][0]); acc[i][1] = fmaf(a, p0.y, acc[i][1]);
                acc[i][2] = fmaf(a, p0.z, acc[i][2]); acc[i][3] = fmaf(a, p0.w, acc[i][3]);
                acc[i][4] = fmaf(a, p1.x, acc[i][4]); acc[i][5] = fmaf(a, p1.y, acc[i][5]);
                acc[i][6] = fmaf(a, p1.z, acc[i][6]); acc[i][7] = fmaf(a, p1.w, acc[i][7]);
            }
        }
        const float4 b2a = *(const float4*)(b2 + tx * 8);
        const float4 b2b = *(const float4*)(b2 + tx * 8 + 4);
        float bias[8] = {b2a.x, b2a.y, b2a.z, b2a.w, b2b.x, b2b.y, b2b.z, b2b.w};
#pragma unroll
        for (int i = 0; i < 4; ++i) {
            float o[8];
#pragma unroll
            for (int j = 0; j < 8; ++j) {
                float v = acc[i][j] + bias[j];
                o[j] = v > 0.f ? v : 0.01f * v;
            }
            float* dst = out + ((size_t)(row0 + ra + i) << 8) + tx * 8;
            *(float4*)(dst)     = make_float4(o[0], o[1], o[2], o[3]);
            *(float4*)(dst + 4) = make_float4(o[4], o[5], o[6], o[7]);
        }
    }
}

// ---------------------------------------------------------------------------
extern "C" void kernel_launch(void* const* d_in, const int* in_sizes, int n_in,
                              void* d_out, int out_size, void* d_ws, size_t ws_size,
                              hipStream_t stream) {
    const float* x0 = (const float*)d_in[0];
    const int*   ed = (const int*)d_in[1];
    const float* Wc = (const float*)d_in[2];
    const float* bc = (const float*)d_in[3];
    const float* W1 = (const float*)d_in[4];
    const float* b1 = (const float*)d_in[5];
    const float* W2 = (const float*)d_in[6];
    const float* b2 = (const float*)d_in[7];

    float* out = (float*)d_out;
    int*   wsi = (int*)d_ws;
    float* wsf = (float*)d_ws;

    if (ws_size >= WS_NEED) {
        int*    degi      = wsi;                 // -> dinv (f32) after scan3
        float*  dinv      = wsf;
        int*    row_start = wsi + OFF_RS;
        int*    cursor    = wsi + OFF_CUR;
        int*    bsum      = wsi + OFF_BS;
        int*    boff      = wsi + OFF_BO;
        int2*   ep        = (int2*)(wsi + OFF_EP);
        u16*    wp        = (u16*)(wsi + WSI_END);
        __half* x0h       = (__half*)((char*)d_ws + X0H_OFF);

        // 8 graphs x 313 blocks; graph = blockIdx&7 -> one XCD per graph.
        int epb = 8 * ((En / 2 + 255) / 256);    // 2504
        k_prep<<<10448, 256, 0, stream>>>(degi, x0h, x0, out, Wc, W1, W2, wp);
        k_deg2<<<epb, 256, 0, stream>>>(ed, degi);
        k_scan1<<<313, 256, 0, stream>>>(degi, row_start, bsum);
        k_scan2<<<1, 512, 0, stream>>>(bsum, boff, row_start);
        k_scan3<<<313, 256, 0, stream>>>(degi, dinv, row_start, boff, cursor);
        k_bin2<<<epb, 256, 0, stream>>>(ed, dinv, cursor, ep);
        k_gather3<<<NROW / 4, 256, 0, stream>>>(
            x0h, dinv, row_start, cursor, ep, out);
        k_fmfma<<<NROW / TM, 256, 0, stream>>>(x0, wp, bc, b1, b2, out);
    } else {
        float* deg = wsf;
        k_canary<<<1, 64, 0, stream>>>(out);
        k_deg_init<<<(NROW + 255) / 256, 256, 0, stream>>>(deg);
        k_deg_count<<<(NEDGE + 255) / 256, 256, 0, stream>>>(ed, deg);
        k_dinv<<<(NROW + 255) / 256, 256, 0, stream>>>(deg);
        k_agg_init<<<(NROW * Fn + 255) / 256, 256, 0, stream>>>(x0, deg, out);
        long long sthreads = (long long)NEDGE * 64;
        k_scatter<<<(int)((sthreads + 255) / 256), 256, 0, stream>>>(ed, deg, x0, out);
        k_fused<<<NROW / TM, 256, 0, stream>>>(x0, Wc, bc, W1, b1, W2, b2, out);
    }
}

// Round 8
// 313.837 us; speedup vs baseline: 1.3260x; 1.0613x over previous
//
#include <hip/hip_runtime.h>
#include <hip/hip_bf16.h>
#include <hip/hip_fp16.h>

// Problem constants: B=8, N=10000, E=160000, F=128, H=256
#define Bn 8
#define Nn 10000
#define En 160000
#define Fn 128
#define Hn 256
#define NROW (Bn * Nn)     // 80,000
#define NEDGE (Bn * En)    // 1,280,000
#define TM 32              // rows per block in fused kernel

// Workspace layout (ints):
//   [0,80000)            deg (int) -> dinv (f32) after k_scan3
//   [80000,160001)       row_start
//   [160004,240004)      cursor
//   [240004,240317)      bsum (313)
//   [240320,240832)      boff (512)
//   [240832,2800832)     ep: int2 {src, bits(dinv[src])} per edge, CSR order
//   then 262,144 B packed weights (u16): Wc split-bf16 [0,32768),
//        W1 f16 [32768,65536), W2 f16 [65536,131072)
//   then 20,480,000 B x0 as f16 [NROW][128].
// R8: gather fused back into the GEMM kernel (k_gfm). R4's fusion failed at
//   3 blocks/CU (51 KB LDS, 12 waves: gather latency-bound, ~1/waves).
//   Post-R6 the chain needs 26.1 KB -> 6 blocks/CU = 24 waves, and blocks in
//   different phases overlap gather-loads with MFMA (separate pipes). Fusion
//   deletes the 82 MB AGG round-trip, the 41 MB scattered f32 x0 read
//   (residual from x0h tile pre-staged in the rs LDS plane), and a launch.
//   out is now write-only (stage C covers all 1024 B/row incl. canary).
#define OFF_RS   80000
#define OFF_CUR  160004
#define OFF_BS   240004
#define OFF_BO   240320
#define OFF_EP   240832
#define WSI_END  2800832
#define WP_U16   131072
#define WP_BYTES ((size_t)WP_U16 * 2)                 // 262,144
#define X0H_BYTES ((size_t)NROW * Fn * 2)             // 20,480,000
#define X0H_OFF  ((size_t)WSI_END * 4 + WP_BYTES)     // 11,465,472
#define WS_NEED  (X0H_OFF + X0H_BYTES)                // 31,945,472

typedef unsigned short u16;
typedef __attribute__((ext_vector_type(8))) short s16x8;
typedef __attribute__((ext_vector_type(8))) _Float16 f16x8;
typedef __attribute__((ext_vector_type(4))) float f32x4;

__device__ __forceinline__ u16 f2bf(float x) {           // RNE f32->bf16
    unsigned u = __float_as_uint(x);
    u += 0x7FFF + ((u >> 16) & 1);
    return (u16)(u >> 16);
}
__device__ __forceinline__ float bf2f(u16 h) {
    return __uint_as_float((unsigned)h << 16);
}
__device__ __forceinline__ u16 f2h(float x) {            // RNE f32->f16 bits
    _Float16 h = (_Float16)x;
    return *(u16*)&h;
}

__device__ __forceinline__ bool edge_is_i64(const int* e) {
    return e[1] == 0 && e[3] == 0;
}
__device__ __forceinline__ int eidx(const int* e, long long i, bool i64) {
    return i64 ? e[2 * i] : e[i];
}

// ---------------------------------------------------------------------------
// k_prep: deg=1 + x0->f16 table (blocks 0..9999) and weight pack
// (blocks 10000..10447).  k-map: k = kt*32 + (l>>4)*8 + j (A-frag map).
// ---------------------------------------------------------------------------
__global__ void k_prep(int* __restrict__ deg, __half* __restrict__ x0h,
                       const float* __restrict__ x0, float* __restrict__ out,
                       const float* __restrict__ Wc, const float* __restrict__ W1,
                       const float* __restrict__ W2, u16* __restrict__ wp) {
    if (blockIdx.x < 10000) {
        int i = blockIdx.x * 256 + threadIdx.x;     // < NROW*32
        if (i < NROW) deg[i] = 1;
        if (i == 0) out[4] = 1000.0f;               // erased by k_gfm stage C
        int r = i >> 5, g = i & 31;
        float4 v = *(const float4*)(x0 + ((size_t)r << 7) + (g << 2));
        __half2 a = __floats2half2_rn(v.x, v.y);
        __half2 b = __floats2half2_rn(v.z, v.w);
        uint2 u;
        u.x = *(unsigned*)&a;
        u.y = *(unsigned*)&b;
        *(uint2*)((char*)x0h + ((size_t)r << 8) + (g << 3)) = u;
    } else {
        int i = (blockIdx.x - 10000) * 256 + threadIdx.x;   // < 114688
        if (i < 16384) {                 // Wc: split-bf16, NT=8
            int j = i & 7, l = (i >> 3) & 63;
            int nt = (i >> 9) & 7, kt = i >> 12;
            int k = kt * 32 + (l >> 4) * 8 + j;
            int n = nt * 16 + (l & 15);
            float v = Wc[(size_t)k * Fn + n];
            u16 hi = f2bf(v);
            u16 lo = f2bf(v - bf2f(hi));
            int o = (kt * 8 + nt) * 1024 + l * 8 + j;
            wp[o] = hi;
            wp[o + 512] = lo;
        } else if (i < 49152) {          // W1: f16 single, NT=16, kt<4
            int idx = i - 16384;
            int j = idx & 7, l = (idx >> 3) & 63;
            int nt = (idx >> 9) & 15, kt = idx >> 13;
            int k = kt * 32 + (l >> 4) * 8 + j;
            int n = nt * 16 + (l & 15);
            wp[32768 + (kt * 16 + nt) * 512 + l * 8 + j] =
                f2h(W1[(size_t)k * Hn + n]);
        } else if (i < 114688) {         // W2: f16 single, NT=16, kt<8
            int idx = i - 49152;
            int j = idx & 7, l = (idx >> 3) & 63;
            int nt = (idx >> 9) & 15, kt = idx >> 13;
            int k = kt * 32 + (l >> 4) * 8 + j;
            int n = nt * 16 + (l & 15);
            wp[65536 + (kt * 16 + nt) * 512 + l * 8 + j] =
                f2h(W2[(size_t)k * Hn + n]);
        }
    }
}

// ---------------------------------------------------------------------------
// Degree count, XCD-partitioned: graph = blockIdx&7 (round-robin -> one XCD
// per graph), 2 edges/thread.
// ---------------------------------------------------------------------------
__global__ void k_deg2(const int* __restrict__ e, int* __restrict__ deg) {
    bool i64 = edge_is_i64(e);
    int b = blockIdx.x & 7;                          // graph == XCD
    int p = (blockIdx.x >> 3) * 256 + threadIdx.x;   // pair idx within graph
    if (p >= En / 2) return;
    int kk = p * 2;
    int d0, d1;
    if (i64) {
        int4 v = *(const int4*)(e + ((long long)(b * 2 + 1) * En + kk) * 2);
        d0 = v.x; d1 = v.z;
    } else {
        int2 v = *(const int2*)(e + (long long)(b * 2 + 1) * En + kk);
        d0 = v.x; d1 = v.y;
    }
    if ((unsigned)d0 < Nn) atomicAdd(&deg[b * Nn + d0], 1);
    if ((unsigned)d1 < Nn) atomicAdd(&deg[b * Nn + d1], 1);
}

// ---------------------------------------------------------------------------
// Exclusive scan of in-degree over 80,000 rows, 3 kernels.
// ---------------------------------------------------------------------------
__global__ void k_scan1(const int* __restrict__ deg,
                        int* __restrict__ row_start, int* __restrict__ bsum) {
    __shared__ int s[256];
    int i = blockIdx.x * 256 + threadIdx.x;
    int v = (i < NROW) ? (deg[i] - 1) : 0;
    s[threadIdx.x] = v;
    __syncthreads();
    for (int off = 1; off < 256; off <<= 1) {
        int t = (threadIdx.x >= off) ? s[threadIdx.x - off] : 0;
        __syncthreads();
        s[threadIdx.x] += t;
        __syncthreads();
    }
    if (i < NROW) row_start[i] = s[threadIdx.x] - v;
    if (threadIdx.x == 255) bsum[blockIdx.x] = s[255];
}

__global__ void k_scan2(const int* __restrict__ bsum, int* __restrict__ boff,
                        int* __restrict__ row_start) {
    __shared__ int s[512];
    int t = threadIdx.x;
    int v = (t < 313) ? bsum[t] : 0;
    s[t] = v;
    __syncthreads();
    for (int off = 1; off < 512; off <<= 1) {
        int u = (t >= off) ? s[t - off] : 0;
        __syncthreads();
        s[t] += u;
        __syncthreads();
    }
    boff[t] = s[t] - v;
    if (t == 511) row_start[NROW] = s[511];
}

__global__ void k_scan3(int* __restrict__ degi, float* __restrict__ dinvf,
                        int* __restrict__ row_start,
                        const int* __restrict__ boff, int* __restrict__ cursor) {
    int i = blockIdx.x * blockDim.x + threadIdx.x;
    if (i >= NROW) return;
    int v = row_start[i] + boff[i >> 8];
    row_start[i] = v;
    cursor[i] = v;
    float d = (float)degi[i];
    dinvf[i] = rsqrtf(d);
}

// ---------------------------------------------------------------------------
// Counting-sort, XCD-partitioned by graph; 8B fused (src, dinv-bits) records.
// ---------------------------------------------------------------------------
__global__ void k_bin2(const int* __restrict__ e, const float* __restrict__ dinv,
                       int* __restrict__ cursor, int2* __restrict__ ep) {
    bool i64 = edge_is_i64(e);
    int b = blockIdx.x & 7;                          // graph == XCD
    int p = (blockIdx.x >> 3) * 256 + threadIdx.x;   // pair idx within graph
    if (p >= En / 2) return;
    int kk = p * 2;
    int s0, s1, d0, d1;
    if (i64) {
        int4 sv = *(const int4*)(e + ((long long)(b * 2) * En + kk) * 2);
        int4 dv = *(const int4*)(e + ((long long)(b * 2 + 1) * En + kk) * 2);
        s0 = sv.x; s1 = sv.z; d0 = dv.x; d1 = dv.z;
    } else {
        int2 sv = *(const int2*)(e + (long long)(b * 2) * En + kk);
        int2 dv = *(const int2*)(e + (long long)(b * 2 + 1) * En + kk);
        s0 = sv.x; s1 = sv.y; d0 = dv.x; d1 = dv.y;
    }
    if ((unsigned)s0 < Nn && (unsigned)d0 < Nn) {
        int g = b * Nn + s0;
        int pos = atomicAdd(&cursor[b * Nn + d0], 1);
        ep[pos] = make_int2(g, __float_as_int(dinv[g]));
    }
    if ((unsigned)s1 < Nn && (unsigned)d1 < Nn) {
        int g = b * Nn + s1;
        int pos = atomicAdd(&cursor[b * Nn + d1], 1);
        ep[pos] = make_int2(g, __float_as_int(dinv[g]));
    }
}

// ---------------------------------------------------------------------------
// k_gfm: fused gather + mixed-precision GEMM chain. 2500 blocks, 256 thr.
// LDS 26,112 B -> 6 blocks/CU (24 waves/CU): gather phase has 2x R4's TLP,
// and co-resident blocks in different phases overlap gather-loads w/ MFMA.
//   rs_ (f16 [32][136]) @0: phase 0 pre-loads x0h tile (coalesced); stage A
//     epilogue reads it as the residual then overwrites with rs (same slot,
//     same thread). ag_hi/ag_lo (bf16 [32][136]) @4352/@8704: written by the
//     gather phase directly. hs (f16 [32][264]) @4352 overlays ag.
// XCD-bijective block swizzle (4x313 + 4x312): each XCD's L2 keeps one
// graph's x0h table (2.56 MB) + ep segment.
// A-frag: row=lane&15, k-slot=(lane>>4)*8+j; C/D: col=lane&15,
// row=(lane>>4)*4+reg (m89/m91-verified).
// ---------------------------------------------------------------------------
__device__ __forceinline__ void g_edge_h(const __half* __restrict__ x0h, int s,
                                         float w, int lane, float& ax, float& ay) {
    __half2 h = *(const __half2*)(x0h + ((size_t)s << 7) + 2 * lane);
    float2 v = __half22float2(h);
    ax = fmaf(w, v.x, ax);
    ay = fmaf(w, v.y, ay);
}
__device__ __forceinline__ void g_pair(const __half* __restrict__ x0h,
                                       int4 pq, int lane, float& ax, float& ay) {
    g_edge_h(x0h, pq.x, __int_as_float(pq.y), lane, ax, ay);
    g_edge_h(x0h, pq.z, __int_as_float(pq.w), lane, ax, ay);
}

__global__ __launch_bounds__(256, 6) void k_gfm(
        const __half* __restrict__ x0h, const float* __restrict__ dinv,
        const int* __restrict__ row_start, const int* __restrict__ row_end,
        const int2* __restrict__ ep, const u16* __restrict__ wp,
        const float* __restrict__ bc, const float* __restrict__ b1,
        const float* __restrict__ b2, float* out) {
    __shared__ __align__(16) u16 sm[13056];
    u16* rs_   = sm;              // [32][136] f16 (x0h tile, then rs)
    u16* ag_hi = sm + 4352;       // [32][136] bf16
    u16* ag_lo = sm + 8704;
    u16* hs    = sm + 4352;       // [32][264] f16, overlays ag

    // bijective XCD chunk swizzle: 2500 = 4*313 + 4*312
    int xcd = blockIdx.x & 7, ii = blockIdx.x >> 3;
    int wg = (xcd < 4 ? xcd * 313 : 1252 + (xcd - 4) * 312) + ii;
    int row0 = wg * TM;

    int t = threadIdx.x;
    int w = t >> 6;               // wave 0..3
    int l = t & 63;
    int lr = l & 15;              // A-frag row / C col
    int lg = l >> 4;              // k-group / C row-group

    // ---- phase 0a: pre-load x0h tile (32 x 256 B) into rs_ plane ----
#pragma unroll
    for (int it = 0; it < 2; ++it) {
        int idx = it * 256 + t;           // 0..511
        int r = idx >> 4, c = idx & 15;   // 16 x 16B chunks per row
        *(uint4*)(rs_ + r * 136 + (c << 3)) =
            *(const uint4*)(x0h + ((size_t)(row0 + r) << 7) + (c << 3));
    }

    // ---- phase 0b: gather — wave w aggregates rows w*8..w*8+7 into LDS ----
#pragma unroll 1
    for (int rr = 0; rr < 8; ++rr) {
        int r = w * 8 + rr;
        int wid = row0 + r;
        int rs = row_start[wid], re = row_end[wid];
        float wd = dinv[wid];
        float ax = 0.f, ay = 0.f;
        int j = rs;
        if (j < re && (j & 1)) {          // peel to int4 alignment
            int2 q = ep[j];
            g_edge_h(x0h, q.x, __int_as_float(q.y), l, ax, ay);
            ++j;
        }
        for (; j + 8 <= re; j += 8) {
            int4 p0 = *(const int4*)(ep + j);
            int4 p1 = *(const int4*)(ep + j + 2);
            int4 p2 = *(const int4*)(ep + j + 4);
            int4 p3 = *(const int4*)(ep + j + 6);
            g_pair(x0h, p0, l, ax, ay);
            g_pair(x0h, p1, l, ax, ay);
            g_pair(x0h, p2, l, ax, ay);
            g_pair(x0h, p3, l, ax, ay);
        }
        if (j + 4 <= re) {
            int4 p0 = *(const int4*)(ep + j);
            int4 p1 = *(const int4*)(ep + j + 2);
            g_pair(x0h, p0, l, ax, ay);
            g_pair(x0h, p1, l, ax, ay);
            j += 4;
        }
        if (j + 2 <= re) {
            int4 p0 = *(const int4*)(ep + j);
            g_pair(x0h, p0, l, ax, ay);
            j += 2;
        }
        if (j < re) {
            int2 q = ep[j];
            g_edge_h(x0h, q.x, __int_as_float(q.y), l, ax, ay);
        }
        g_edge_h(x0h, wid, wd, l, ax, ay);    // self-loop
        float sx = wd * ax, sy = wd * ay;
        u16 h0 = f2bf(sx), h1 = f2bf(sy);
        u16 l0 = f2bf(sx - bf2f(h0)), l1 = f2bf(sy - bf2f(h1));
        ((unsigned*)ag_hi)[r * 68 + l] = (unsigned)h0 | ((unsigned)h1 << 16);
        ((unsigned*)ag_lo)[r * 68 + l] = (unsigned)l0 | ((unsigned)l1 << 16);
    }
    __syncthreads();

    // ---- stage A: conv = ag@Wc (32x128, split-bf16); nt in {2w,2w+1} ----
    {
        f32x4 acc[2][2];
#pragma unroll
        for (int mi = 0; mi < 2; ++mi)
#pragma unroll
            for (int ni = 0; ni < 2; ++ni) acc[mi][ni] = (f32x4){0.f, 0.f, 0.f, 0.f};
#pragma unroll
        for (int kt = 0; kt < 4; ++kt) {
            int ka = kt * 32 + lg * 8;
            s16x8 a0h = *(const s16x8*)(ag_hi + lr * 136 + ka);
            s16x8 a0l = *(const s16x8*)(ag_lo + lr * 136 + ka);
            s16x8 a1h = *(const s16x8*)(ag_hi + (16 + lr) * 136 + ka);
            s16x8 a1l = *(const s16x8*)(ag_lo + (16 + lr) * 136 + ka);
#pragma unroll
            for (int ni = 0; ni < 2; ++ni) {
                int nt = 2 * w + ni;
                const u16* bp = wp + (kt * 8 + nt) * 1024 + l * 8;
                s16x8 bh = *(const s16x8*)(bp);
                s16x8 bl = *(const s16x8*)(bp + 512);
                acc[0][ni] = __builtin_amdgcn_mfma_f32_16x16x32_bf16(a0h, bl, acc[0][ni], 0, 0, 0);
                acc[0][ni] = __builtin_amdgcn_mfma_f32_16x16x32_bf16(a0l, bh, acc[0][ni], 0, 0, 0);
                acc[0][ni] = __builtin_amdgcn_mfma_f32_16x16x32_bf16(a0h, bh, acc[0][ni], 0, 0, 0);
                acc[1][ni] = __builtin_amdgcn_mfma_f32_16x16x32_bf16(a1h, bl, acc[1][ni], 0, 0, 0);
                acc[1][ni] = __builtin_amdgcn_mfma_f32_16x16x32_bf16(a1l, bh, acc[1][ni], 0, 0, 0);
                acc[1][ni] = __builtin_amdgcn_mfma_f32_16x16x32_bf16(a1h, bh, acc[1][ni], 0, 0, 0);
            }
        }
        // epilogue: rs = relu(conv + bc) + x0h (read own slot, overwrite)
#pragma unroll
        for (int ni = 0; ni < 2; ++ni) {
            int col = (2 * w + ni) * 16 + lr;
            float bias = bc[col];
#pragma unroll
            for (int mi = 0; mi < 2; ++mi)
#pragma unroll
                for (int r = 0; r < 4; ++r) {
                    int row = mi * 16 + lg * 4 + r;
                    float xr = (float)*(const _Float16*)(rs_ + row * 136 + col);
                    float v = acc[mi][ni][r] + bias;
                    v = fmaxf(v, 0.f) + xr;
                    rs_[row * 136 + col] = f2h(v);
                }
        }
    }
    __syncthreads();   // ag reads done (hs overlays); rs visible

    // ---- stage B: hs = leaky(rs@W1 + b1) (32x256, f16); nt in {4w..4w+3} ----
    {
        const u16* w1p = wp + 32768;
        f32x4 acc[2][4];
#pragma unroll
        for (int mi = 0; mi < 2; ++mi)
#pragma unroll
            for (int ni = 0; ni < 4; ++ni) acc[mi][ni] = (f32x4){0.f, 0.f, 0.f, 0.f};
#pragma unroll
        for (int kt = 0; kt < 4; ++kt) {
            int ka = kt * 32 + lg * 8;
            f16x8 a0 = *(const f16x8*)(rs_ + lr * 136 + ka);
            f16x8 a1 = *(const f16x8*)(rs_ + (16 + lr) * 136 + ka);
#pragma unroll
            for (int ni = 0; ni < 4; ++ni) {
                int nt = 4 * w + ni;
                f16x8 b = *(const f16x8*)(w1p + (kt * 16 + nt) * 512 + l * 8);
                acc[0][ni] = __builtin_amdgcn_mfma_f32_16x16x32_f16(a0, b, acc[0][ni], 0, 0, 0);
                acc[1][ni] = __builtin_amdgcn_mfma_f32_16x16x32_f16(a1, b, acc[1][ni], 0, 0, 0);
            }
        }
#pragma unroll
        for (int ni = 0; ni < 4; ++ni) {
            int col = (4 * w + ni) * 16 + lr;
            float bias = b1[col];
#pragma unroll
            for (int mi = 0; mi < 2; ++mi)
#pragma unroll
                for (int r = 0; r < 4; ++r) {
                    int row = mi * 16 + lg * 4 + r;
                    float v = acc[mi][ni][r] + bias;
                    v = v > 0.f ? v : 0.01f * v;
                    hs[row * 264 + col] = f2h(v);
                }
        }
    }
    __syncthreads();

    // ---- stage C: out = leaky(hs@W2 + b2) (32x256, f16), K=256 ----
    {
        const u16* w2p = wp + 65536;
        f32x4 acc[2][4];
#pragma unroll
        for (int mi = 0; mi < 2; ++mi)
#pragma unroll
            for (int ni = 0; ni < 4; ++ni) acc[mi][ni] = (f32x4){0.f, 0.f, 0.f, 0.f};
#pragma unroll
        for (int kt = 0; kt < 8; ++kt) {
            int ka = kt * 32 + lg * 8;
            f16x8 a0 = *(const f16x8*)(hs + lr * 264 + ka);
            f16x8 a1 = *(const f16x8*)(hs + (16 + lr) * 264 + ka);
#pragma unroll
            for (int ni = 0; ni < 4; ++ni) {
                int nt = 4 * w + ni;
                f16x8 b = *(const f16x8*)(w2p + (kt * 16 + nt) * 512 + l * 8);
                acc[0][ni] = __builtin_amdgcn_mfma_f32_16x16x32_f16(a0, b, acc[0][ni], 0, 0, 0);
                acc[1][ni] = __builtin_amdgcn_mfma_f32_16x16x32_f16(a1, b, acc[1][ni], 0, 0, 0);
            }
        }
#pragma unroll
        for (int ni = 0; ni < 4; ++ni) {
            int col = (4 * w + ni) * 16 + lr;
            float bias = b2[col];
#pragma unroll
            for (int mi = 0; mi < 2; ++mi)
#pragma unroll
                for (int r = 0; r < 4; ++r) {
                    int row = mi * 16 + lg * 4 + r;
                    float v = acc[mi][ni][r] + bias;
                    v = v > 0.f ? v : 0.01f * v;
                    out[((size_t)(row0 + row) << 8) + col] = v;
                }
        }
    }
}

// ---------------------------------------------------------------------------
// Full fallback (tiny workspace): float degree + atomic scatter + f32 fused.
// ---------------------------------------------------------------------------
__global__ void k_canary(float* out) {
    if (threadIdx.x == 0 && blockIdx.x == 0) out[4] = 1000.0f;
}
__global__ void k_deg_init(float* __restrict__ deg) {
    int i = blockIdx.x * blockDim.x + threadIdx.x;
    if (i < NROW) deg[i] = 1.0f;
}
__global__ void k_deg_count(const int* __restrict__ e, float* __restrict__ deg) {
    bool i64 = edge_is_i64(e);
    int i = blockIdx.x * blockDim.x + threadIdx.x;
    if (i >= NEDGE) return;
    int b = i / En, k = i - b * En;
    int dst = eidx(e, (long long)(b * 2 + 1) * En + k, i64);
    if ((unsigned)dst < Nn) atomicAdd(&deg[b * Nn + dst], 1.0f);
}
__global__ void k_dinv(float* __restrict__ deg) {
    int i = blockIdx.x * blockDim.x + threadIdx.x;
    if (i < NROW) deg[i] = rsqrtf(deg[i]);
}
__global__ void k_agg_init(const float* __restrict__ x0,
                           const float* __restrict__ dinv,
                           float* __restrict__ out) {
    int i = blockIdx.x * blockDim.x + threadIdx.x;
    if (i >= NROW * Fn) return;
    int r = i >> 7;
    int c = i & 127;
    float dv = dinv[r];
    out[((size_t)r << 8) + c] = dv * dv * x0[i];
}
__global__ void k_scatter(const int* __restrict__ e,
                          const float* __restrict__ dinv,
                          const float* __restrict__ x0,
                          float* __restrict__ out) {
    bool i64 = edge_is_i64(e);
    long long gid = (long long)blockIdx.x * blockDim.x + threadIdx.x;
    int eid = (int)(gid >> 6);
    int lane = (int)(gid & 63);
    if (eid >= NEDGE) return;
    int b = eid / En, k = eid - b * En;
    int src = eidx(e, (long long)(b * 2) * En + k, i64);
    int dst = eidx(e, (long long)(b * 2 + 1) * En + k, i64);
    if ((unsigned)src >= Nn || (unsigned)dst >= Nn) return;
    float nrm = dinv[b * Nn + src] * dinv[b * Nn + dst];
    const float2 vf =
        *(const float2*)(x0 + ((size_t)(b * Nn + src) << 7) + 2 * lane);
    float* p = out + ((size_t)(b * Nn + dst) << 8) + 2 * lane;
    atomicAdd(p, nrm * vf.x);
    atomicAdd(p + 1, nrm * vf.y);
}

__global__ __launch_bounds__(256, 3) void k_fused(
        const float* __restrict__ x0,
        const float* __restrict__ Wc, const float* __restrict__ bc,
        const float* __restrict__ W1, const float* __restrict__ b1,
        const float* __restrict__ W2, const float* __restrict__ b2,
        float* out) {
    __shared__ float smem[12352];
    float (*rs)[Fn + 1] = (float (*)[Fn + 1])smem;
    float (*ag)[Fn + 1] = (float (*)[Fn + 1])(smem + 4128);
    float (*hs)[Hn + 1] = (float (*)[Hn + 1])(smem + 4128);

    int row0 = blockIdx.x * TM;
    int t = threadIdx.x;
    int tx = t & 31;
    int ty = t >> 5;
    int ra = ty * 4;

    for (int i = t; i < TM * Fn; i += 256) {
        int r = i >> 7, c = i & 127;
        ag[r][c] = out[((size_t)(row0 + r) << 8) + c];
    }
    __syncthreads();
    {
        float acc[4][4] = {};
#pragma unroll 4
        for (int k = 0; k < Fn; ++k) {
            float a0 = ag[ra + 0][k], a1 = ag[ra + 1][k],
                  a2 = ag[ra + 2][k], a3 = ag[ra + 3][k];
            const float4 b = *(const float4*)(Wc + k * Fn + tx * 4);
            acc[0][0] = fmaf(a0, b.x, acc[0][0]); acc[0][1] = fmaf(a0, b.y, acc[0][1]);
            acc[0][2] = fmaf(a0, b.z, acc[0][2]); acc[0][3] = fmaf(a0, b.w, acc[0][3]);
            acc[1][0] = fmaf(a1, b.x, acc[1][0]); acc[1][1] = fmaf(a1, b.y, acc[1][1]);
            acc[1][2] = fmaf(a1, b.z, acc[1][2]); acc[1][3] = fmaf(a1, b.w, acc[1][3]);
            acc[2][0] = fmaf(a2, b.x, acc[2][0]); acc[2][1] = fmaf(a2, b.y, acc[2][1]);
            acc[2][2] = fmaf(a2, b.z, acc[2][2]); acc[2][3] = fmaf(a2, b.w, acc[2][3]);
            acc[3][0] = fmaf(a3, b.x, acc[3][0]); acc[3][1] = fmaf(a3, b.y, acc[3][1]);
            acc[3][2] = fmaf(a3, b.z, acc[3][2]); acc[3][3] = fmaf(a3, b.w, acc[3][3]);
        }
        const float4 bcv = *(const float4*)(bc + tx * 4);
        __syncthreads();
#pragma unroll
        for (int i = 0; i < 4; ++i) {
            const float4 xv =
                *(const float4*)(x0 + (size_t)(row0 + ra + i) * Fn + tx * 4);
            rs[ra + i][tx * 4 + 0] = fmaxf(acc[i][0] + bcv.x, 0.f) + xv.x;
            rs[ra + i][tx * 4 + 1] = fmaxf(acc[i][1] + bcv.y, 0.f) + xv.y;
            rs[ra + i][tx * 4 + 2] = fmaxf(acc[i][2] + bcv.z, 0.f) + xv.z;
            rs[ra + i][tx * 4 + 3] = fmaxf(acc[i][3] + bcv.w, 0.f) + xv.w;
        }
    }
    __syncthreads();
    {
        float acc[4][8] = {};
#pragma unroll 2
        for (int k = 0; k < Fn; ++k) {
            float a0 = rs[ra + 0][k], a1 = rs[ra + 1][k],
                  a2 = rs[ra + 2][k], a3 = rs[ra + 3][k];
            const float4 p0 = *(const float4*)(W1 + k * Hn + tx * 8);
            const float4 p1 = *(const float4*)(W1 + k * Hn + tx * 8 + 4);
#pragma unroll
            for (int i = 0; i < 4; ++i) {
                float a = (i == 0) ? a0 : (i == 1) ? a1 : (i == 2) ? a2 : a3;
                acc[i][0] = fmaf(a, p0.x, acc[i][0]); acc[i][1] = fmaf(a, p0.y, acc[i][1]);
                acc[i][2] = fmaf(a, p0.z, acc[i][2]); acc[i][3] = fmaf(a, p0.w, acc[i][3]);
                acc[i][4] = fmaf(a, p1.x, acc[i][4]); acc[i][5] = fmaf(a, p1.y, acc[i][5]);
                acc[i][6] = fmaf(a, p1.z, acc[i][6]); acc[i][7] = fmaf(a, p1.w, acc[i][7]);
            }
        }
        const float4 b1a = *(const float4*)(b1 + tx * 8);
        const float4 b1b = *(const float4*)(b1 + tx * 8 + 4);
        float bias[8] = {b1a.x, b1a.y, b1a.z, b1a.w, b1b.x, b1b.y, b1b.z, b1b.w};
#pragma unroll
        for (int i = 0; i < 4; ++i)
#pragma unroll
            for (int j = 0; j < 8; ++j) {
                float h = acc[i][j] + bias[j];
                hs[ra + i][tx * 8 + j] = h > 0.f ? h : 0.01f * h;
            }
    }
    __syncthreads();
    {
        float acc[4][8] = {};
#pragma unroll 2
        for (int k = 0; k < Hn; ++k) {
            float a0 = hs[ra + 0][k], a1 = hs[ra + 1][k],
                  a2 = hs[ra + 2][k], a3 = hs[ra + 3][k];
            const float4 p0 = *(const float4*)(W2 + k * Hn + tx * 8);
            const float4 p1 = *(const float4*)(W2 + k * Hn + tx * 8 + 4);
#pragma unroll
            for (int i = 0; i < 4; ++i) {
                float a = (i == 0) ? a0 : (i == 1) ? a1 : (i == 2) ? a2 : a3;
                acc[i][0] = fmaf(a, p0.x, acc[i][0]); acc[i][1] = fmaf(a, p0.y, acc[i][1]);
                acc[i][2] = fmaf(a, p0.z, acc[i][2]); acc[i][3] = fmaf(a, p0.w, acc[i][3]);
                acc[i][4] = fmaf(a, p1.x, acc[i][4]); acc[i][5] = fmaf(a, p1.y, acc[i][5]);
                acc[i][6] = fmaf(a, p1.z, acc[i][6]); acc[i][7] = fmaf(a, p1.w, acc[i][7]);
            }
        }
        const float4 b2a = *(const float4*)(b2 + tx * 8);
        const float4 b2b = *(const float4*)(b2 + tx * 8 + 4);
        float bias[8] = {b2a.x, b2a.y, b2a.z, b2a.w, b2b.x, b2b.y, b2b.z, b2b.w};
#pragma unroll
        for (int i = 0; i < 4; ++i) {
            float o[8];
#pragma unroll
            for (int j = 0; j < 8; ++j) {
                float v = acc[i][j] + bias[j];
                o[j] = v > 0.f ? v : 0.01f * v;
            }
            float* dst = out + ((size_t)(row0 + ra + i) << 8) + tx * 8;
            *(float4*)(dst)     = make_float4(o[0], o[1], o[2], o[3]);
            *(float4*)(dst + 4) = make_float4(o[4], o[5], o[6], o[7]);
        }
    }
}

// ---------------------------------------------------------------------------
extern "C" void kernel_launch(void* const* d_in, const int* in_sizes, int n_in,
                              void* d_out, int out_size, void* d_ws, size_t ws_size,
                              hipStream_t stream) {
    const float* x0 = (const float*)d_in[0];
    const int*   ed = (const int*)d_in[1];
    const float* Wc = (const float*)d_in[2];
    const float* bc = (const float*)d_in[3];
    const float* W1 = (const float*)d_in[4];
    const float* b1 = (const float*)d_in[5];
    const float* W2 = (const float*)d_in[6];
    const float* b2 = (const float*)d_in[7];

    float* out = (float*)d_out;
    int*   wsi = (int*)d_ws;
    float* wsf = (float*)d_ws;

    if (ws_size >= WS_NEED) {
        int*    degi      = wsi;                 // -> dinv (f32) after scan3
        float*  dinv      = wsf;
        int*    row_start = wsi + OFF_RS;
        int*    cursor    = wsi + OFF_CUR;
        int*    bsum      = wsi + OFF_BS;
        int*    boff      = wsi + OFF_BO;
        int2*   ep        = (int2*)(wsi + OFF_EP);
        u16*    wp        = (u16*)(wsi + WSI_END);
        __half* x0h       = (__half*)((char*)d_ws + X0H_OFF);

        // 8 graphs x 313 blocks; graph = blockIdx&7 -> one XCD per graph.
        int epb = 8 * ((En / 2 + 255) / 256);    // 2504
        k_prep<<<10448, 256, 0, stream>>>(degi, x0h, x0, out, Wc, W1, W2, wp);
        k_deg2<<<epb, 256, 0, stream>>>(ed, degi);
        k_scan1<<<313, 256, 0, stream>>>(degi, row_start, bsum);
        k_scan2<<<1, 512, 0, stream>>>(bsum, boff, row_start);
        k_scan3<<<313, 256, 0, stream>>>(degi, dinv, row_start, boff, cursor);
        k_bin2<<<epb, 256, 0, stream>>>(ed, dinv, cursor, ep);
        k_gfm<<<NROW / TM, 256, 0, stream>>>(
            x0h, dinv, row_start, cursor, ep, wp, bc, b1, b2, out);
    } else {
        float* deg = wsf;
        k_canary<<<1, 64, 0, stream>>>(out);
        k_deg_init<<<(NROW + 255) / 256, 256, 0, stream>>>(deg);
        k_deg_count<<<(NEDGE + 255) / 256, 256, 0, stream>>>(ed, deg);
        k_dinv<<<(NROW + 255) / 256, 256, 0, stream>>>(deg);
        k_agg_init<<<(NROW * Fn + 255) / 256, 256, 0, stream>>>(x0, deg, out);
        long long sthreads = (long long)NEDGE * 64;
        k_scatter<<<(int)((sthreads + 255) / 256), 256, 0, stream>>>(ed, deg, x0, out);
        k_fused<<<NROW / TM, 256, 0, stream>>>(x0, Wc, bc, W1, b1, W2, b2, out);
    }
}